// Round 4
// baseline (835.560 us; speedup 1.0000x reference)
//
#include <hip/hip_runtime.h>
#include <math.h>

// Problem constants (match reference)
constexpr int Bb = 8, Cc = 256, Nn = 2048, Hh = 4, HD = 64, KK = 64;
constexpr int Mm = Bb * Nn;  // 16384
constexpr float NEG = -1e30f;

// ---------------------------------------------------------------------------
// K0: combine projection weights:  cw[part*256 + j][c'] = sum_c Wsrc[c'][c] * in_proj_w[part*256+j][c]
// so that qkv = xt @ cw^T + in_proj_b  (one fused GEMM instead of 6)
// ---------------------------------------------------------------------------
__global__ __launch_bounds__(256) void combine_w_k(
    const float* __restrict__ WQ, const float* __restrict__ WK,
    const float* __restrict__ WV, const float* __restrict__ inw,
    float* __restrict__ cw)
{
    __shared__ float ssub[256];
    const int row = blockIdx.x;          // 0..767
    const int part = row >> 8;
    const float* Wsrc = (part == 0) ? WQ : (part == 1) ? WK : WV;
    const int tid = threadIdx.x;
    ssub[tid] = inw[(size_t)row * 256 + tid];
    __syncthreads();
    float acc = 0.f;
    for (int c = 0; c < 256; c++)
        acc += Wsrc[(size_t)tid * 256 + c] * ssub[c];
    cw[(size_t)row * 256 + tid] = acc;   // cw[row][c'=tid]
}

// ---------------------------------------------------------------------------
// Generic tiled GEMM: out[m, j] = sum_k A[m,k] * W[j,k] + bias[j]  (+ epilogue)
// BM=BN=64, KT=16, 256 threads, 4x4 micro-tile per thread.
// AGATHER: A is x laid out [B, C, N]  (A[m,k] = x[b, k, n])
// EPI: 0 none, 1 exact GELU, 2 += x[b, j, n] (residual from [B,C,N]), 3 += res[m, j]
// ---------------------------------------------------------------------------
template<bool AGATHER, int EPI>
__global__ __launch_bounds__(256) void gemm_k(
    const float* __restrict__ A, const float* __restrict__ W,
    const float* __restrict__ bias, const float* __restrict__ res,
    float* __restrict__ out, int Nout, int Kdim)
{
    __shared__ __align__(16) float As[16][64];
    __shared__ __align__(16) float Ws[16][64];
    const int tid = threadIdx.x;
    const int m0 = blockIdx.x * 64, n0 = blockIdx.y * 64;
    const int tx = tid & 15, ty = tid >> 4;
    const int r0 = ty * 4, c0 = tx * 4;
    float acc[4][4] = {};

    int bidx = 0, nseq0 = 0;
    if (AGATHER) { bidx = m0 / Nn; nseq0 = m0 % Nn; }

    for (int kt = 0; kt < Kdim; kt += 16) {
        if (AGATHER) {
            const int kq = tid >> 6;      // 0..3
            const int r  = tid & 63;      // coalesced along n
            #pragma unroll
            for (int kk = 0; kk < 16; kk += 4)
                As[kk + kq][r] = A[(size_t)bidx * Kdim * Nn + (size_t)(kt + kk + kq) * Nn + nseq0 + r];
        } else {
            const int r  = tid >> 2;
            const int k4 = (tid & 3) * 4;
            const float4 v = *(const float4*)(A + (size_t)(m0 + r) * Kdim + kt + k4);
            As[k4 + 0][r] = v.x; As[k4 + 1][r] = v.y; As[k4 + 2][r] = v.z; As[k4 + 3][r] = v.w;
        }
        {
            const int c  = tid >> 2;
            const int k4 = (tid & 3) * 4;
            const float4 v = *(const float4*)(W + (size_t)(n0 + c) * Kdim + kt + k4);
            Ws[k4 + 0][c] = v.x; Ws[k4 + 1][c] = v.y; Ws[k4 + 2][c] = v.z; Ws[k4 + 3][c] = v.w;
        }
        __syncthreads();
        #pragma unroll
        for (int k = 0; k < 16; k++) {
            const float4 a4 = *(const float4*)&As[k][r0];
            const float4 b4 = *(const float4*)&Ws[k][c0];
            const float av[4] = {a4.x, a4.y, a4.z, a4.w};
            const float bv[4] = {b4.x, b4.y, b4.z, b4.w};
            #pragma unroll
            for (int i = 0; i < 4; i++)
                #pragma unroll
                for (int j = 0; j < 4; j++)
                    acc[i][j] += av[i] * bv[j];
        }
        __syncthreads();
    }

    #pragma unroll
    for (int i = 0; i < 4; i++) {
        const int m = m0 + r0 + i;
        float4 o;
        float* po = (float*)&o;
        #pragma unroll
        for (int j = 0; j < 4; j++) {
            const int jn = n0 + c0 + j;
            float v = acc[i][j] + bias[jn];
            if (EPI == 1) {
                v = 0.5f * v * (1.0f + erff(v * 0.70710678118f));
            } else if (EPI == 2) {
                const int be = m >> 11, ne = m & (Nn - 1);
                v += res[((size_t)be * Nout + jn) * Nn + ne];
            } else if (EPI == 3) {
                v += res[(size_t)m * Nout + jn];
            }
            po[j] = v;
        }
        *(float4*)(out + (size_t)m * Nout + n0 + c0) = o;
    }
}

// ---------------------------------------------------------------------------
// K2: flash attention. Block = 256 thr handles one (b,h) x 64 q-rows.
// Online softmax over key tiles of 64; key-padding mask from lengths[b].
// qkv layout: [M, 768] = [q(256) | k(256) | v(256)] per row.
// ---------------------------------------------------------------------------
__global__ __launch_bounds__(256) void attn_k(
    const float* __restrict__ qkv, const int* __restrict__ lengths,
    float* __restrict__ outp)
{
    __shared__ __align__(16) float Qs[HD][68];   // [dim][qrow], stride 68 keeps float4 alignment
    __shared__ __align__(16) float KVs[HD][68];  // K phase: [dim][key]; V phase: [key][dim]
    __shared__ float Ss[64][65];
    __shared__ float m_s[64], l_s[64], f_s[64];

    const int tid = threadIdx.x;
    const int qt = blockIdx.x;
    const int bh = blockIdx.y;
    const int b = bh >> 2, h = bh & (Hh - 1);
    const int len = lengths[b];
    const int tx = tid & 15, ty = tid >> 4;
    const int r0 = ty * 4, c0 = tx * 4;
    const int lr = tid >> 2;          // load row 0..63
    const int lq = (tid & 3) * 16;    // load dim start

    {   // stage Q tile (transposed: [dim][row])
        const float* src = qkv + (size_t)(b * Nn + qt * 64 + lr) * 768 + h * 64 + lq;
        #pragma unroll
        for (int ii = 0; ii < 16; ii += 4) {
            const float4 v = *(const float4*)(src + ii);
            Qs[lq + ii + 0][lr] = v.x; Qs[lq + ii + 1][lr] = v.y;
            Qs[lq + ii + 2][lr] = v.z; Qs[lq + ii + 3][lr] = v.w;
        }
    }
    if (tid < 64) { m_s[tid] = NEG; l_s[tid] = 0.f; }

    float acc[4][4] = {};
    const int ktmax = (len + 63) >> 6;   // len >= N/2, so tile 0 is always fully valid
    for (int kt = 0; kt < ktmax; ++kt) {
        __syncthreads();   // prev PV done (and Q/m/l ready on first iter)
        {   // stage K tile [dim][key]
            const float* src = qkv + (size_t)(b * Nn + kt * 64 + lr) * 768 + 256 + h * 64 + lq;
            #pragma unroll
            for (int ii = 0; ii < 16; ii += 4) {
                const float4 v = *(const float4*)(src + ii);
                KVs[lq + ii + 0][lr] = v.x; KVs[lq + ii + 1][lr] = v.y;
                KVs[lq + ii + 2][lr] = v.z; KVs[lq + ii + 3][lr] = v.w;
            }
        }
        __syncthreads();
        // S = Q K^T / sqrt(64)
        float sacc[4][4] = {};
        #pragma unroll 16
        for (int k = 0; k < HD; k++) {
            const float4 a4 = *(const float4*)&Qs[k][r0];
            const float4 b4 = *(const float4*)&KVs[k][c0];
            const float av[4] = {a4.x, a4.y, a4.z, a4.w};
            const float bv[4] = {b4.x, b4.y, b4.z, b4.w};
            #pragma unroll
            for (int i = 0; i < 4; i++)
                #pragma unroll
                for (int j = 0; j < 4; j++)
                    sacc[i][j] += av[i] * bv[j];
        }
        #pragma unroll
        for (int i = 0; i < 4; i++)
            #pragma unroll
            for (int j = 0; j < 4; j++)
                Ss[r0 + i][c0 + j] = sacc[i][j] * 0.125f;
        __syncthreads();
        // online softmax: 4 threads per row, 16 cols each
        {
            const int r = tid >> 2, tg = tid & 3;
            const int kbase = kt * 64 + tg * 16;
            float sv[16];
            float mt = NEG;
            #pragma unroll
            for (int cc = 0; cc < 16; cc++) {
                const float s = (kbase + cc < len) ? Ss[r][tg * 16 + cc] : NEG;
                sv[cc] = s;
                mt = fmaxf(mt, s);
            }
            mt = fmaxf(mt, __shfl_xor(mt, 1));
            mt = fmaxf(mt, __shfl_xor(mt, 2));
            const float mo = m_s[r];
            const float mn = fmaxf(mo, mt);
            float sum = 0.f;
            #pragma unroll
            for (int cc = 0; cc < 16; cc++) {
                const float p = __expf(sv[cc] - mn);
                Ss[r][tg * 16 + cc] = p;
                sum += p;
            }
            sum += __shfl_xor(sum, 1);
            sum += __shfl_xor(sum, 2);
            if (tg == 0) {
                const float f = __expf(mo - mn);
                f_s[r] = f;
                l_s[r] = l_s[r] * f + sum;
                m_s[r] = mn;
            }
        }
        __syncthreads();
        {   // stage V tile [key][dim]  (reuses KVs; K consumed above)
            const float* src = qkv + (size_t)(b * Nn + kt * 64 + lr) * 768 + 512 + h * 64 + lq;
            #pragma unroll
            for (int ii = 0; ii < 16; ii += 4) {
                const float4 v = *(const float4*)(src + ii);
                KVs[lr][lq + ii + 0] = v.x; KVs[lr][lq + ii + 1] = v.y;
                KVs[lr][lq + ii + 2] = v.z; KVs[lr][lq + ii + 3] = v.w;
            }
        }
        #pragma unroll
        for (int i = 0; i < 4; i++) {   // rescale running accumulator
            const float f = f_s[r0 + i];
            #pragma unroll
            for (int j = 0; j < 4; j++) acc[i][j] *= f;
        }
        __syncthreads();
        // O += P V
        #pragma unroll 8
        for (int kk = 0; kk < 64; kk++) {
            const float4 v4 = *(const float4*)&KVs[kk][c0];
            const float vv[4] = {v4.x, v4.y, v4.z, v4.w};
            const float p0 = Ss[r0 + 0][kk];
            const float p1 = Ss[r0 + 1][kk];
            const float p2 = Ss[r0 + 2][kk];
            const float p3 = Ss[r0 + 3][kk];
            #pragma unroll
            for (int j = 0; j < 4; j++) {
                acc[0][j] += p0 * vv[j];
                acc[1][j] += p1 * vv[j];
                acc[2][j] += p2 * vv[j];
                acc[3][j] += p3 * vv[j];
            }
        }
    }
    #pragma unroll
    for (int i = 0; i < 4; i++) {
        const float inv = 1.f / l_s[r0 + i];
        const int m = b * Nn + qt * 64 + r0 + i;
        float4 o;
        o.x = acc[i][0] * inv; o.y = acc[i][1] * inv;
        o.z = acc[i][2] * inv; o.w = acc[i][3] * inv;
        *(float4*)(outp + (size_t)m * Cc + h * 64 + c0) = o;
    }
}

// ---------------------------------------------------------------------------
// LayerNorm over C=256: one wave per row (4 elems/lane), 4 rows/block
// ---------------------------------------------------------------------------
__global__ __launch_bounds__(256) void ln_k(
    const float* __restrict__ in, const float* __restrict__ w,
    const float* __restrict__ bc, float* __restrict__ out)
{
    const int wave = threadIdx.x >> 6, lane = threadIdx.x & 63;
    const int row = blockIdx.x * 4 + wave;
    const float* p = in + (size_t)row * 256;
    const float v0 = p[lane], v1 = p[lane + 64], v2 = p[lane + 128], v3 = p[lane + 192];
    float s = v0 + v1 + v2 + v3;
    float s2 = v0 * v0 + v1 * v1 + v2 * v2 + v3 * v3;
    #pragma unroll
    for (int off = 32; off > 0; off >>= 1) {
        s  += __shfl_xor(s, off);
        s2 += __shfl_xor(s2, off);
    }
    const float mean = s * (1.f / 256.f);
    const float var  = s2 * (1.f / 256.f) - mean * mean;
    const float rstd = rsqrtf(var + 1e-5f);
    float* q = out + (size_t)row * 256;
    q[lane]       = (v0 - mean) * rstd * w[lane]       + bc[lane];
    q[lane + 64]  = (v1 - mean) * rstd * w[lane + 64]  + bc[lane + 64];
    q[lane + 128] = (v2 - mean) * rstd * w[lane + 128] + bc[lane + 128];
    q[lane + 192] = (v3 - mean) * rstd * w[lane + 192] + bc[lane + 192];
}

// ---------------------------------------------------------------------------
// K9: masked softmax over sequence dim per (b, cluster); output [B, K, N]
// ---------------------------------------------------------------------------
__global__ __launch_bounds__(256) void smax_k(
    const float* __restrict__ logits, const int* __restrict__ lengths,
    float* __restrict__ outp)
{
    __shared__ float red[8];
    const int bk = blockIdx.x;              // b*64 + kc
    const int b = bk >> 6, kc = bk & 63;
    const int len = lengths[b];
    const int tid = threadIdx.x;
    const int lane = tid & 63, wv = tid >> 6;

    float m = NEG;
    for (int n = tid; n < len; n += 256)
        m = fmaxf(m, logits[((size_t)b * Nn + n) * KK + kc]);
    #pragma unroll
    for (int off = 32; off > 0; off >>= 1) m = fmaxf(m, __shfl_xor(m, off));
    if (lane == 0) red[wv] = m;
    __syncthreads();
    m = fmaxf(fmaxf(red[0], red[1]), fmaxf(red[2], red[3]));

    float s = 0.f;
    for (int n = tid; n < len; n += 256)
        s += __expf(logits[((size_t)b * Nn + n) * KK + kc] - m);
    #pragma unroll
    for (int off = 32; off > 0; off >>= 1) s += __shfl_xor(s, off);
    if (lane == 0) red[4 + wv] = s;
    __syncthreads();
    s = red[4] + red[5] + red[6] + red[7];
    const float inv = 1.f / s;

    for (int n = tid; n < Nn; n += 256) {
        float o = 0.f;
        if (n < len)
            o = __expf(logits[((size_t)b * Nn + n) * KK + kc] - m) * inv;
        outp[((size_t)b * KK + kc) * Nn + n] = o;
    }
}

// ---------------------------------------------------------------------------
extern "C" void kernel_launch(void* const* d_in, const int* in_sizes, int n_in,
                              void* d_out, int out_size, void* d_ws, size_t ws_size,
                              hipStream_t stream)
{
    (void)in_sizes; (void)n_in; (void)out_size; (void)ws_size;
    const float* x      = (const float*)d_in[0];
    const int*   lens   = (const int*)d_in[1];
    const float* WQ     = (const float*)d_in[2];
    const float* WK     = (const float*)d_in[3];
    const float* WV     = (const float*)d_in[4];
    const float* in_w   = (const float*)d_in[5];
    const float* in_b   = (const float*)d_in[6];
    const float* op_w   = (const float*)d_in[7];
    const float* op_b   = (const float*)d_in[8];
    const float* ln1w   = (const float*)d_in[9];
    const float* ln1b   = (const float*)d_in[10];
    const float* ln2w   = (const float*)d_in[11];
    const float* ln2b   = (const float*)d_in[12];
    const float* ff1w   = (const float*)d_in[13];
    const float* ff1b   = (const float*)d_in[14];
    const float* ff2w   = (const float*)d_in[15];
    const float* ff2b   = (const float*)d_in[16];
    const float* prw    = (const float*)d_in[17];
    const float* prb    = (const float*)d_in[18];
    float* out = (float*)d_out;

    // workspace layout (lifetime-scheduled reuse; peak ~97 MB)
    char* ws = (char*)d_ws;
    float* qkv      = (float*)(ws + 0);                        // [M,768] 48 MB
    float* ffmid    = (float*)(ws + 0);                        // [M,512] 32 MB (after attn)
    float* y2       = (float*)(ws + (size_t)32 * 1024 * 1024); // [M,256] 16 MB
    float* attn_out = (float*)(ws + (size_t)48 * 1024 * 1024); // [M,256] 16 MB
    float* logits   = (float*)(ws + (size_t)48 * 1024 * 1024); // [M,64]   4 MB (after out_proj)
    float* y1       = (float*)(ws + (size_t)64 * 1024 * 1024); // [M,256] 16 MB
    float* h2       = (float*)(ws + (size_t)64 * 1024 * 1024); // [M,256] 16 MB (after ln1)
    float* h1       = (float*)(ws + (size_t)80 * 1024 * 1024); // [M,256] 16 MB
    float* cw       = (float*)(ws + (size_t)96 * 1024 * 1024); // [768,256] 768 KB

    combine_w_k<<<768, 256, 0, stream>>>(WQ, WK, WV, in_w, cw);
    gemm_k<true, 0><<<dim3(Mm / 64, 768 / 64), 256, 0, stream>>>(x, cw, in_b, nullptr, qkv, 768, 256);
    attn_k<<<dim3(Nn / 64, Bb * Hh), 256, 0, stream>>>(qkv, lens, attn_out);
    gemm_k<false, 2><<<dim3(Mm / 64, 256 / 64), 256, 0, stream>>>(attn_out, op_w, op_b, x, y1, 256, 256);
    ln_k<<<Mm / 4, 256, 0, stream>>>(y1, ln1w, ln1b, h1);
    gemm_k<false, 1><<<dim3(Mm / 64, 512 / 64), 256, 0, stream>>>(h1, ff1w, ff1b, nullptr, ffmid, 512, 256);
    gemm_k<false, 3><<<dim3(Mm / 64, 256 / 64), 256, 0, stream>>>(ffmid, ff2w, ff2b, h1, y2, 256, 512);
    ln_k<<<Mm / 4, 256, 0, stream>>>(y2, ln2w, ln2b, h2);
    gemm_k<false, 0><<<dim3(Mm / 64, 64 / 64), 256, 0, stream>>>(h2, prw, prb, nullptr, logits, 64, 256);
    smax_k<<<Bb * KK, 256, 0, stream>>>(logits, lens, out);
}

// Round 6
// 515.011 us; speedup vs baseline: 1.6224x; 1.6224x over previous
//
#include <hip/hip_runtime.h>
#include <math.h>

// Problem constants (match reference)
constexpr int Bb = 8, Cc = 256, Nn = 2048, Hh = 4, HD = 64, KK = 64;
constexpr int Mm = Bb * Nn;  // 16384
constexpr float NEG = -1e30f;

typedef unsigned short u16;
typedef __attribute__((ext_vector_type(8))) short bf16x8;   // 8 bf16 = 4 VGPRs (guide §3)
typedef __attribute__((ext_vector_type(4))) float f32x4;    // MFMA C/D

static __device__ __forceinline__ u16 f2bf(float x) {       // fp32 -> bf16 RNE
    union { float f; unsigned u; } v; v.f = x;
    const unsigned r = v.u + 0x7FFFu + ((v.u >> 16) & 1u);
    return (u16)(r >> 16);
}

// XOR-swizzled byte offset inside a [64 rows][64 bf16] = 8KB LDS tile (G4 fix)
#define SWZB(row, col) ((((row) * 128) + ((col) * 2)) ^ (((row) & 7) << 4))

// ---------------------------------------------------------------------------
// K0: combine projection weights (unchanged)
// ---------------------------------------------------------------------------
__global__ __launch_bounds__(256) void combine_w_k(
    const float* __restrict__ WQ, const float* __restrict__ WK,
    const float* __restrict__ WV, const float* __restrict__ inw,
    float* __restrict__ cw)
{
    __shared__ float ssub[256];
    const int row = blockIdx.x;          // 0..767
    const int part = row >> 8;
    const float* Wsrc = (part == 0) ? WQ : (part == 1) ? WK : WV;
    const int tid = threadIdx.x;
    ssub[tid] = inw[(size_t)row * 256 + tid];
    __syncthreads();
    float acc = 0.f;
    for (int c = 0; c < 256; c++)
        acc += Wsrc[(size_t)tid * 256 + c] * ssub[c];
    cw[(size_t)row * 256 + tid] = acc;
}

// ---------------------------------------------------------------------------
// Generic tiled fp32 GEMM (unchanged) — used for out_proj/ff1/ff2/proj
// ---------------------------------------------------------------------------
template<bool AGATHER, int EPI>
__global__ __launch_bounds__(256) void gemm_k(
    const float* __restrict__ A, const float* __restrict__ W,
    const float* __restrict__ bias, const float* __restrict__ res,
    float* __restrict__ out, int Nout, int Kdim)
{
    __shared__ __align__(16) float As[16][64];
    __shared__ __align__(16) float Ws[16][64];
    const int tid = threadIdx.x;
    const int m0 = blockIdx.x * 64, n0 = blockIdx.y * 64;
    const int tx = tid & 15, ty = tid >> 4;
    const int r0 = ty * 4, c0 = tx * 4;
    float acc[4][4] = {};

    int bidx = 0, nseq0 = 0;
    if (AGATHER) { bidx = m0 / Nn; nseq0 = m0 % Nn; }

    for (int kt = 0; kt < Kdim; kt += 16) {
        if (AGATHER) {
            const int kq = tid >> 6;
            const int r  = tid & 63;
            #pragma unroll
            for (int kk = 0; kk < 16; kk += 4)
                As[kk + kq][r] = A[(size_t)bidx * Kdim * Nn + (size_t)(kt + kk + kq) * Nn + nseq0 + r];
        } else {
            const int r  = tid >> 2;
            const int k4 = (tid & 3) * 4;
            const float4 v = *(const float4*)(A + (size_t)(m0 + r) * Kdim + kt + k4);
            As[k4 + 0][r] = v.x; As[k4 + 1][r] = v.y; As[k4 + 2][r] = v.z; As[k4 + 3][r] = v.w;
        }
        {
            const int c  = tid >> 2;
            const int k4 = (tid & 3) * 4;
            const float4 v = *(const float4*)(W + (size_t)(n0 + c) * Kdim + kt + k4);
            Ws[k4 + 0][c] = v.x; Ws[k4 + 1][c] = v.y; Ws[k4 + 2][c] = v.z; Ws[k4 + 3][c] = v.w;
        }
        __syncthreads();
        #pragma unroll
        for (int k = 0; k < 16; k++) {
            const float4 a4 = *(const float4*)&As[k][r0];
            const float4 b4 = *(const float4*)&Ws[k][c0];
            const float av[4] = {a4.x, a4.y, a4.z, a4.w};
            const float bv[4] = {b4.x, b4.y, b4.z, b4.w};
            #pragma unroll
            for (int i = 0; i < 4; i++)
                #pragma unroll
                for (int j = 0; j < 4; j++)
                    acc[i][j] += av[i] * bv[j];
        }
        __syncthreads();
    }

    #pragma unroll
    for (int i = 0; i < 4; i++) {
        const int m = m0 + r0 + i;
        float4 o;
        float* po = (float*)&o;
        #pragma unroll
        for (int j = 0; j < 4; j++) {
            const int jn = n0 + c0 + j;
            float v = acc[i][j] + bias[jn];
            if (EPI == 1) {
                v = 0.5f * v * (1.0f + erff(v * 0.70710678118f));
            } else if (EPI == 2) {
                const int be = m >> 11, ne = m & (Nn - 1);
                v += res[((size_t)be * Nout + jn) * Nn + ne];
            } else if (EPI == 3) {
                v += res[(size_t)m * Nout + jn];
            }
            po[j] = v;
        }
        *(float4*)(out + (size_t)m * Nout + n0 + c0) = o;
    }
}

// ---------------------------------------------------------------------------
// K1b: qkv GEMM (A gathered from x[B,C,N]) writing bf16 Q[bh][n][d],
// K[bh][n][d], and V^T[bh][d][n] — attention-ready layouts, no fp32 qkv.
// ---------------------------------------------------------------------------
__global__ __launch_bounds__(256) void gemm_qkv_k(
    const float* __restrict__ A, const float* __restrict__ W,
    const float* __restrict__ bias,
    u16* __restrict__ qb, u16* __restrict__ kb, u16* __restrict__ vtb)
{
    constexpr int Kdim = 256;
    __shared__ __align__(16) float As[16][64];
    __shared__ __align__(16) float Ws[16][64];
    const int tid = threadIdx.x;
    const int m0 = blockIdx.x * 64, n0 = blockIdx.y * 64;
    const int tx = tid & 15, ty = tid >> 4;
    const int r0 = ty * 4, c0 = tx * 4;
    float acc[4][4] = {};

    const int bidx = m0 / Nn, nseq0 = m0 % Nn;

    for (int kt = 0; kt < Kdim; kt += 16) {
        {
            const int kq = tid >> 6;
            const int r  = tid & 63;
            #pragma unroll
            for (int kk = 0; kk < 16; kk += 4)
                As[kk + kq][r] = A[(size_t)bidx * Kdim * Nn + (size_t)(kt + kk + kq) * Nn + nseq0 + r];
        }
        {
            const int c  = tid >> 2;
            const int k4 = (tid & 3) * 4;
            const float4 v = *(const float4*)(W + (size_t)(n0 + c) * Kdim + kt + k4);
            Ws[k4 + 0][c] = v.x; Ws[k4 + 1][c] = v.y; Ws[k4 + 2][c] = v.z; Ws[k4 + 3][c] = v.w;
        }
        __syncthreads();
        #pragma unroll
        for (int k = 0; k < 16; k++) {
            const float4 a4 = *(const float4*)&As[k][r0];
            const float4 b4 = *(const float4*)&Ws[k][c0];
            const float av[4] = {a4.x, a4.y, a4.z, a4.w};
            const float bv[4] = {b4.x, b4.y, b4.z, b4.w};
            #pragma unroll
            for (int i = 0; i < 4; i++)
                #pragma unroll
                for (int j = 0; j < 4; j++)
                    acc[i][j] += av[i] * bv[j];
        }
        __syncthreads();
    }

    const int part = n0 >> 8;            // 0=q 1=k 2=v
    const int h    = (n0 >> 6) & 3;      // head
    const int b    = m0 >> 11;
    const int bh   = b * 4 + h;
    // add bias
    #pragma unroll
    for (int i = 0; i < 4; i++)
        #pragma unroll
        for (int j = 0; j < 4; j++)
            acc[i][j] += bias[n0 + c0 + j];

    if (part < 2) {
        u16* dst = (part == 0) ? qb : kb;
        #pragma unroll
        for (int i = 0; i < 4; i++) {
            const int nrow = (m0 & (Nn - 1)) + r0 + i;
            ushort4 o = make_ushort4(f2bf(acc[i][0]), f2bf(acc[i][1]),
                                     f2bf(acc[i][2]), f2bf(acc[i][3]));
            *(ushort4*)(dst + ((size_t)bh * Nn + nrow) * 64 + c0) = o;
        }
    } else {
        const int nrow0 = (m0 & (Nn - 1)) + r0;
        #pragma unroll
        for (int j = 0; j < 4; j++) {
            ushort4 o = make_ushort4(f2bf(acc[0][j]), f2bf(acc[1][j]),
                                     f2bf(acc[2][j]), f2bf(acc[3][j]));
            *(ushort4*)(vtb + ((size_t)bh * 64 + c0 + j) * Nn + nrow0) = o;
        }
    }
}

// ---------------------------------------------------------------------------
// K2: MFMA flash attention. 256 thr = 4 waves; block = (qtile 64, bh).
// mfma_f32_16x16x32_bf16: A/B k-contiguous (lane%16 = row/col, k=8*(lane/16)+e),
// C/D col=lane&15, row=4*(lane>>4)+reg [guide §3, m89/m91].
// Wave w owns S/O rows [16w,16w+16): softmax state in registers, P wave-local.
// ---------------------------------------------------------------------------
__global__ __launch_bounds__(256) void attn_mfma_k(
    const u16* __restrict__ qb, const u16* __restrict__ kb,
    const u16* __restrict__ vtb, const int* __restrict__ lengths,
    float* __restrict__ outp)
{
    __shared__ __align__(16) char QsB[8192];   // [64 q][64 d] bf16, swizzled
    __shared__ __align__(16) char KsB[8192];   // [64 k][64 d]
    __shared__ __align__(16) char VtB[8192];   // [64 d][64 k]
    __shared__ __align__(16) char PsB[8192];   // [64 q][64 k]

    const int tid = threadIdx.x;
    const int qt = blockIdx.x;
    const int bh = blockIdx.y;
    const int b  = bh >> 2;
    const int len = lengths[b];
    const int w  = tid >> 6;
    const int l  = tid & 63;
    const int g  = l >> 4;
    const int li = l & 15;

    // stage Q tile (512 x 16B chunks)
    for (int c = tid; c < 512; c += 256) {
        const int row = c >> 3, blk = c & 7;
        const uint4 v = *(const uint4*)(qb + ((size_t)bh * Nn + qt * 64 + row) * 64 + blk * 8);
        *(uint4*)(QsB + SWZB(row, blk * 8)) = v;
    }
    __syncthreads();
    // persistent Q A-frags: rows 16w+li, k = 32ks + 8g + e
    bf16x8 aq[2];
    #pragma unroll
    for (int ks = 0; ks < 2; ks++)
        aq[ks] = *(const bf16x8*)(QsB + SWZB(16 * w + li, 32 * ks + 8 * g));

    f32x4 oacc[4];
    #pragma unroll
    for (int df = 0; df < 4; df++) oacc[df] = f32x4{0.f, 0.f, 0.f, 0.f};
    float m_run[4], l_run[4];
    #pragma unroll
    for (int r = 0; r < 4; r++) { m_run[r] = NEG; l_run[r] = 0.f; }

    const int ktmax = (len + 63) >> 6;
    for (int kt = 0; kt < ktmax; ++kt) {
        __syncthreads();   // prev tile's K/V reads complete
        for (int c = tid; c < 512; c += 256) {      // K tile [key][dim]
            const int row = c >> 3, blk = c & 7;
            const uint4 v = *(const uint4*)(kb + ((size_t)bh * Nn + kt * 64 + row) * 64 + blk * 8);
            *(uint4*)(KsB + SWZB(row, blk * 8)) = v;
        }
        for (int c = tid; c < 512; c += 256) {      // V^T tile [dim][key]
            const int row = c >> 3, blk = c & 7;
            const uint4 v = *(const uint4*)(vtb + ((size_t)bh * 64 + row) * Nn + kt * 64 + blk * 8);
            *(uint4*)(VtB + SWZB(row, blk * 8)) = v;
        }
        __syncthreads();

        // S = Q K^T
        f32x4 s[4];
        #pragma unroll
        for (int cf = 0; cf < 4; cf++) {
            f32x4 z = f32x4{0.f, 0.f, 0.f, 0.f};
            #pragma unroll
            for (int ks = 0; ks < 2; ks++) {
                const bf16x8 bk = *(const bf16x8*)(KsB + SWZB(16 * cf + li, 32 * ks + 8 * g));
                z = __builtin_amdgcn_mfma_f32_16x16x32_bf16(aq[ks], bk, z, 0, 0, 0);
            }
            s[cf] = z;
        }
        // scale + key mask + tile row-max
        float mt[4];
        #pragma unroll
        for (int r = 0; r < 4; r++) mt[r] = NEG;
        #pragma unroll
        for (int cf = 0; cf < 4; cf++) {
            const bool ok = (kt * 64 + 16 * cf + li) < len;
            #pragma unroll
            for (int r = 0; r < 4; r++) {
                const float v = ok ? s[cf][r] * 0.125f : NEG;
                s[cf][r] = v;
                mt[r] = fmaxf(mt[r], v);
            }
        }
        #pragma unroll
        for (int off = 1; off < 16; off <<= 1)
            #pragma unroll
            for (int r = 0; r < 4; r++) mt[r] = fmaxf(mt[r], __shfl_xor(mt[r], off));

        float f[4], sum[4];
        #pragma unroll
        for (int r = 0; r < 4; r++) {
            const float mn = fmaxf(m_run[r], mt[r]);
            f[r] = __expf(m_run[r] - mn);
            m_run[r] = mn;
            sum[r] = 0.f;
        }
        // P = exp(S - m); write bf16 to wave-private P rows (no barrier needed)
        #pragma unroll
        for (int cf = 0; cf < 4; cf++)
            #pragma unroll
            for (int r = 0; r < 4; r++) {
                const float p = __expf(s[cf][r] - m_run[r]);
                sum[r] += p;
                const int row = 16 * w + 4 * g + r;
                *(u16*)(PsB + SWZB(row, 16 * cf + li)) = f2bf(p);
            }
        #pragma unroll
        for (int off = 1; off < 16; off <<= 1)
            #pragma unroll
            for (int r = 0; r < 4; r++) sum[r] += __shfl_xor(sum[r], off);
        #pragma unroll
        for (int r = 0; r < 4; r++) l_run[r] = l_run[r] * f[r] + sum[r];
        // rescale O
        #pragma unroll
        for (int df = 0; df < 4; df++)
            #pragma unroll
            for (int r = 0; r < 4; r++) oacc[df][r] *= f[r];
        // O += P V  (A = own P rows, B = V^T rows = dims)
        bf16x8 ap[2];
        #pragma unroll
        for (int ks = 0; ks < 2; ks++)
            ap[ks] = *(const bf16x8*)(PsB + SWZB(16 * w + li, 32 * ks + 8 * g));
        #pragma unroll
        for (int df = 0; df < 4; df++)
            #pragma unroll
            for (int ks = 0; ks < 2; ks++) {
                const bf16x8 bv = *(const bf16x8*)(VtB + SWZB(16 * df + li, 32 * ks + 8 * g));
                oacc[df] = __builtin_amdgcn_mfma_f32_16x16x32_bf16(ap[ks], bv, oacc[df], 0, 0, 0);
            }
    }
    // epilogue: normalize, store fp32 attn_out [m][256]
    #pragma unroll
    for (int r = 0; r < 4; r++) {
        const float inv = 1.f / l_run[r];
        const int qrow = qt * 64 + 16 * w + 4 * g + r;
        const size_t base = ((size_t)b * Nn + qrow) * Cc + (bh & 3) * 64;
        #pragma unroll
        for (int df = 0; df < 4; df++)
            outp[base + 16 * df + li] = oacc[df][r] * inv;
    }
}

// ---------------------------------------------------------------------------
// LayerNorm (unchanged)
// ---------------------------------------------------------------------------
__global__ __launch_bounds__(256) void ln_k(
    const float* __restrict__ in, const float* __restrict__ w,
    const float* __restrict__ bc, float* __restrict__ out)
{
    const int wave = threadIdx.x >> 6, lane = threadIdx.x & 63;
    const int row = blockIdx.x * 4 + wave;
    const float* p = in + (size_t)row * 256;
    const float v0 = p[lane], v1 = p[lane + 64], v2 = p[lane + 128], v3 = p[lane + 192];
    float s = v0 + v1 + v2 + v3;
    float s2 = v0 * v0 + v1 * v1 + v2 * v2 + v3 * v3;
    #pragma unroll
    for (int off = 32; off > 0; off >>= 1) {
        s  += __shfl_xor(s, off);
        s2 += __shfl_xor(s2, off);
    }
    const float mean = s * (1.f / 256.f);
    const float var  = s2 * (1.f / 256.f) - mean * mean;
    const float rstd = rsqrtf(var + 1e-5f);
    float* q = out + (size_t)row * 256;
    q[lane]       = (v0 - mean) * rstd * w[lane]       + bc[lane];
    q[lane + 64]  = (v1 - mean) * rstd * w[lane + 64]  + bc[lane + 64];
    q[lane + 128] = (v2 - mean) * rstd * w[lane + 128] + bc[lane + 128];
    q[lane + 192] = (v3 - mean) * rstd * w[lane + 192] + bc[lane + 192];
}

// ---------------------------------------------------------------------------
// K9: masked sequence softmax (unchanged)
// ---------------------------------------------------------------------------
__global__ __launch_bounds__(256) void smax_k(
    const float* __restrict__ logits, const int* __restrict__ lengths,
    float* __restrict__ outp)
{
    __shared__ float red[8];
    const int bk = blockIdx.x;
    const int b = bk >> 6, kc = bk & 63;
    const int len = lengths[b];
    const int tid = threadIdx.x;
    const int lane = tid & 63, wv = tid >> 6;

    float m = NEG;
    for (int n = tid; n < len; n += 256)
        m = fmaxf(m, logits[((size_t)b * Nn + n) * KK + kc]);
    #pragma unroll
    for (int off = 32; off > 0; off >>= 1) m = fmaxf(m, __shfl_xor(m, off));
    if (lane == 0) red[wv] = m;
    __syncthreads();
    m = fmaxf(fmaxf(red[0], red[1]), fmaxf(red[2], red[3]));

    float s = 0.f;
    for (int n = tid; n < len; n += 256)
        s += __expf(logits[((size_t)b * Nn + n) * KK + kc] - m);
    #pragma unroll
    for (int off = 32; off > 0; off >>= 1) s += __shfl_xor(s, off);
    if (lane == 0) red[4 + wv] = s;
    __syncthreads();
    s = red[4] + red[5] + red[6] + red[7];
    const float inv = 1.f / s;

    for (int n = tid; n < Nn; n += 256) {
        float o = 0.f;
        if (n < len)
            o = __expf(logits[((size_t)b * Nn + n) * KK + kc] - m) * inv;
        outp[((size_t)b * KK + kc) * Nn + n] = o;
    }
}

// ---------------------------------------------------------------------------
extern "C" void kernel_launch(void* const* d_in, const int* in_sizes, int n_in,
                              void* d_out, int out_size, void* d_ws, size_t ws_size,
                              hipStream_t stream)
{
    (void)in_sizes; (void)n_in; (void)out_size; (void)ws_size;
    const float* x      = (const float*)d_in[0];
    const int*   lens   = (const int*)d_in[1];
    const float* WQ     = (const float*)d_in[2];
    const float* WK     = (const float*)d_in[3];
    const float* WV     = (const float*)d_in[4];
    const float* in_w   = (const float*)d_in[5];
    const float* in_b   = (const float*)d_in[6];
    const float* op_w   = (const float*)d_in[7];
    const float* op_b   = (const float*)d_in[8];
    const float* ln1w   = (const float*)d_in[9];
    const float* ln1b   = (const float*)d_in[10];
    const float* ln2w   = (const float*)d_in[11];
    const float* ln2b   = (const float*)d_in[12];
    const float* ff1w   = (const float*)d_in[13];
    const float* ff1b   = (const float*)d_in[14];
    const float* ff2w   = (const float*)d_in[15];
    const float* ff2b   = (const float*)d_in[16];
    const float* prw    = (const float*)d_in[17];
    const float* prb    = (const float*)d_in[18];
    float* out = (float*)d_out;

    // workspace layout (lifetime-scheduled reuse; peak ~97 MB)
    char* ws = (char*)d_ws;
    u16*   qbuf     = (u16*)(ws + 0);                          // [32][2048][64] bf16 8 MB
    u16*   kbuf     = (u16*)(ws + (size_t) 8 * 1024 * 1024);   // 8 MB
    u16*   vtbuf    = (u16*)(ws + (size_t)16 * 1024 * 1024);   // V^T 8 MB
    float* ffmid    = (float*)(ws + 0);                        // [M,512] 32 MB (after attn)
    float* y2       = (float*)(ws + (size_t)32 * 1024 * 1024); // [M,256] 16 MB
    float* attn_out = (float*)(ws + (size_t)48 * 1024 * 1024); // [M,256] 16 MB
    float* logits   = (float*)(ws + (size_t)48 * 1024 * 1024); // [M,64] 4 MB (after out_proj)
    float* y1       = (float*)(ws + (size_t)64 * 1024 * 1024); // [M,256] 16 MB
    float* h2       = (float*)(ws + (size_t)64 * 1024 * 1024); // [M,256] 16 MB (after ln1)
    float* h1       = (float*)(ws + (size_t)80 * 1024 * 1024); // [M,256] 16 MB
    float* cw       = (float*)(ws + (size_t)96 * 1024 * 1024); // [768,256] 768 KB

    combine_w_k<<<768, 256, 0, stream>>>(WQ, WK, WV, in_w, cw);
    gemm_qkv_k<<<dim3(Mm / 64, 768 / 64), 256, 0, stream>>>(x, cw, in_b, qbuf, kbuf, vtbuf);
    attn_mfma_k<<<dim3(Nn / 64, Bb * Hh), 256, 0, stream>>>(qbuf, kbuf, vtbuf, lens, attn_out);
    gemm_k<false, 2><<<dim3(Mm / 64, 256 / 64), 256, 0, stream>>>(attn_out, op_w, op_b, x, y1, 256, 256);
    ln_k<<<Mm / 4, 256, 0, stream>>>(y1, ln1w, ln1b, h1);
    gemm_k<false, 1><<<dim3(Mm / 64, 512 / 64), 256, 0, stream>>>(h1, ff1w, ff1b, nullptr, ffmid, 512, 256);
    gemm_k<false, 3><<<dim3(Mm / 64, 256 / 64), 256, 0, stream>>>(ffmid, ff2w, ff2b, h1, y2, 256, 512);
    ln_k<<<Mm / 4, 256, 0, stream>>>(y2, ln2w, ln2b, h2);
    gemm_k<false, 0><<<dim3(Mm / 64, 64 / 64), 256, 0, stream>>>(h2, prw, prb, nullptr, logits, 64, 256);
    smax_k<<<Bb * KK, 256, 0, stream>>>(logits, lens, out);
}

// Round 9
// 328.345 us; speedup vs baseline: 2.5448x; 1.5685x over previous
//
#include <hip/hip_runtime.h>
#include <math.h>

// Problem constants (match reference)
constexpr int Bb = 8, Cc = 256, Nn = 2048, Hh = 4, HD = 64, KK = 64;
constexpr int Mm = Bb * Nn;  // 16384
constexpr float NEG = -1e30f;

typedef unsigned short u16;
typedef __attribute__((ext_vector_type(8))) short bf16x8;   // 8 bf16 = 4 VGPRs
typedef __attribute__((ext_vector_type(4))) float f32x4;    // MFMA C/D

static __device__ __forceinline__ u16 f2bf(float x) {       // fp32 -> bf16 RNE
    union { float f; unsigned u; } v; v.f = x;
    const unsigned r = v.u + 0x7FFFu + ((v.u >> 16) & 1u);
    return (u16)(r >> 16);
}

// XOR-swizzled byte offset in a [rows][64 bf16] LDS tile (validated in attn r6)
#define SWZB(row, col) ((((row) * 128) + ((col) * 2)) ^ (((row) & 7) << 4))

// ---------------------------------------------------------------------------
// xt_k: x [B,C,N] fp32 -> xb [B,N,C] bf16  (64x64 LDS-tiled transpose)
// ---------------------------------------------------------------------------
__global__ __launch_bounds__(256) void xt_k(
    const float* __restrict__ x, u16* __restrict__ xb)
{
    __shared__ float Ts[64][65];
    const int tid = threadIdx.x;
    const int n0 = blockIdx.x * 64, c0 = blockIdx.y * 64, b = blockIdx.z;
    for (int c = tid; c < 1024; c += 256) {
        const int row = c >> 4, col = (c & 15) * 4;
        const float4 v = *(const float4*)(x + ((size_t)b * Cc + c0 + row) * Nn + n0 + col);
        Ts[row][col + 0] = v.x; Ts[row][col + 1] = v.y;
        Ts[row][col + 2] = v.z; Ts[row][col + 3] = v.w;
    }
    __syncthreads();
    for (int c = tid; c < 1024; c += 256) {
        const int nr = c >> 4, cc = (c & 15) * 4;
        const ushort4 o = make_ushort4(f2bf(Ts[cc + 0][nr]), f2bf(Ts[cc + 1][nr]),
                                       f2bf(Ts[cc + 2][nr]), f2bf(Ts[cc + 3][nr]));
        *(ushort4*)(xb + ((size_t)b * Nn + n0 + nr) * Cc + c0 + cc) = o;
    }
}

// ---------------------------------------------------------------------------
// K0: combine projection weights -> bf16 cwb[768][256]
// ---------------------------------------------------------------------------
__global__ __launch_bounds__(256) void combine_w_k(
    const float* __restrict__ WQ, const float* __restrict__ WK,
    const float* __restrict__ WV, const float* __restrict__ inw,
    u16* __restrict__ cwb)
{
    __shared__ float ssub[256];
    const int row = blockIdx.x;          // 0..767
    const int part = row >> 8;
    const float* Wsrc = (part == 0) ? WQ : (part == 1) ? WK : WV;
    const int tid = threadIdx.x;
    ssub[tid] = inw[(size_t)row * 256 + tid];
    __syncthreads();
    float acc = 0.f;
    for (int c = 0; c < 256; c++)
        acc += Wsrc[(size_t)tid * 256 + c] * ssub[c];
    cwb[(size_t)row * 256 + tid] = f2bf(acc);
}

// ---------------------------------------------------------------------------
// cvt4_k: four fp32->bf16 weight conversions in one launch
// ---------------------------------------------------------------------------
__global__ __launch_bounds__(256) void cvt4_k(
    const float* __restrict__ s0, u16* __restrict__ d0, int c0_,
    const float* __restrict__ s1, u16* __restrict__ d1, int c1_,
    const float* __restrict__ s2, u16* __restrict__ d2, int c2_,
    const float* __restrict__ s3, u16* __restrict__ d3, int c3_)
{
    const int q0 = c0_ >> 2, q1 = c1_ >> 2, q2 = c2_ >> 2, q3 = c3_ >> 2;
    const int total = q0 + q1 + q2 + q3;
    for (int i = blockIdx.x * 256 + threadIdx.x; i < total; i += gridDim.x * 256) {
        const float* s; u16* d; int idx = i;
        if (idx < q0)            { s = s0; d = d0; }
        else if ((idx -= q0) < q1) { s = s1; d = d1; }
        else if ((idx -= q1) < q2) { s = s2; d = d2; }
        else { idx -= q2;          s = s3; d = d3; }
        const float4 v = ((const float4*)s)[idx];
        ((ushort4*)d)[idx] = make_ushort4(f2bf(v.x), f2bf(v.y), f2bf(v.z), f2bf(v.w));
    }
}

// ---------------------------------------------------------------------------
// gemm_mfma_k: D[m,j] = sum_k A[m,k]*W[j,k] + bias[j]  (bf16 in, fp32 acc)
// BM=128 BN=64 BK=64, 256 thr = 4 waves (2Mx2N), wave tile 64x32.
// Fragment layout identical to validated attn kernel (16x16x32_bf16).
// EPI: 0 qkv-split (Q/K bf16 [bh][n][d], V^T bf16 [bh][d][n])
//      1 +bias +x[b,j,n] residual -> fp32      (out_proj)
//      2 +bias, GELU -> bf16                   (ff1)
//      3 +bias +res[m,j] fp32 residual -> fp32 (ff2)
//      4 +bias -> fp32                         (proj)
// ---------------------------------------------------------------------------
template<int EPI>
__global__ __launch_bounds__(256) void gemm_mfma_k(
    const u16* __restrict__ A, const u16* __restrict__ W,
    const float* __restrict__ bias, const float* __restrict__ res,
    float* __restrict__ fout, u16* __restrict__ bout,
    u16* __restrict__ kout, u16* __restrict__ vtout,
    int Nout, int Kdim)
{
    __shared__ __align__(16) char AsB[128 * 128];  // 128 rows x 64 bf16, swizzled
    __shared__ __align__(16) char WsB[64 * 128];   // 64 rows x 64 bf16

    const int tid = threadIdx.x;
    const int m0 = blockIdx.x * 128, n0 = blockIdx.y * 64;
    const int w = tid >> 6, l = tid & 63, g = l >> 4, li = l & 15;
    const int wm = w >> 1, wn = w & 1;

    f32x4 acc[4][2];
    #pragma unroll
    for (int mf = 0; mf < 4; mf++)
        #pragma unroll
        for (int nf = 0; nf < 2; nf++) acc[mf][nf] = f32x4{0.f, 0.f, 0.f, 0.f};

    for (int kt = 0; kt < Kdim; kt += 64) {
        __syncthreads();   // prev k-step frag reads complete
        for (int c = tid; c < 1024; c += 256) {       // stage A 128x64
            const int row = c >> 3, blk = c & 7;
            const uint4 v = *(const uint4*)(A + (size_t)(m0 + row) * Kdim + kt + blk * 8);
            *(uint4*)(AsB + SWZB(row, blk * 8)) = v;
        }
        for (int c = tid; c < 512; c += 256) {        // stage W 64x64
            const int row = c >> 3, blk = c & 7;
            const uint4 v = *(const uint4*)(W + (size_t)(n0 + row) * Kdim + kt + blk * 8);
            *(uint4*)(WsB + SWZB(row, blk * 8)) = v;
        }
        __syncthreads();
        #pragma unroll
        for (int ks = 0; ks < 2; ks++) {
            bf16x8 af[4], bfr[2];
            #pragma unroll
            for (int mf = 0; mf < 4; mf++)
                af[mf] = *(const bf16x8*)(AsB + SWZB(wm * 64 + mf * 16 + li, ks * 32 + 8 * g));
            #pragma unroll
            for (int nf = 0; nf < 2; nf++)
                bfr[nf] = *(const bf16x8*)(WsB + SWZB(wn * 32 + nf * 16 + li, ks * 32 + 8 * g));
            #pragma unroll
            for (int mf = 0; mf < 4; mf++)
                #pragma unroll
                for (int nf = 0; nf < 2; nf++)
                    acc[mf][nf] = __builtin_amdgcn_mfma_f32_16x16x32_bf16(af[mf], bfr[nf], acc[mf][nf], 0, 0, 0);
        }
    }

    // ---------------- epilogue ----------------
    if (EPI == 0) {
        const int part = n0 >> 8;            // 0=q 1=k 2=v
        const int h    = (n0 >> 6) & 3;
        const int b    = m0 >> 11;
        const int bh   = b * 4 + h;
        #pragma unroll
        for (int mf = 0; mf < 4; mf++)
            #pragma unroll
            for (int nf = 0; nf < 2; nf++) {
                const int d  = wn * 32 + nf * 16 + li;          // 0..63 head dim
                const float bv = bias[n0 + d];
                const int nr0 = (m0 & (Nn - 1)) + wm * 64 + mf * 16 + 4 * g;
                if (part < 2) {
                    u16* dst = (part == 0) ? bout : kout;
                    #pragma unroll
                    for (int r = 0; r < 4; r++)
                        dst[((size_t)bh * Nn + nr0 + r) * 64 + d] = f2bf(acc[mf][nf][r] + bv);
                } else {
                    const ushort4 o = make_ushort4(
                        f2bf(acc[mf][nf][0] + bv), f2bf(acc[mf][nf][1] + bv),
                        f2bf(acc[mf][nf][2] + bv), f2bf(acc[mf][nf][3] + bv));
                    *(ushort4*)(vtout + ((size_t)bh * 64 + d) * Nn + nr0) = o;
                }
            }
    } else {
        #pragma unroll
        for (int mf = 0; mf < 4; mf++)
            #pragma unroll
            for (int nf = 0; nf < 2; nf++) {
                const int j = n0 + wn * 32 + nf * 16 + li;
                const float bv = bias[j];
                #pragma unroll
                for (int r = 0; r < 4; r++) {
                    const int m = m0 + wm * 64 + mf * 16 + 4 * g + r;
                    float v = acc[mf][nf][r] + bv;
                    if (EPI == 1) {
                        v += res[((size_t)(m >> 11) * Cc + j) * Nn + (m & (Nn - 1))];
                        fout[(size_t)m * Nout + j] = v;
                    } else if (EPI == 2) {
                        v = 0.5f * v * (1.0f + erff(v * 0.70710678118f));
                        bout[(size_t)m * Nout + j] = f2bf(v);
                    } else if (EPI == 3) {
                        v += res[(size_t)m * Nout + j];
                        fout[(size_t)m * Nout + j] = v;
                    } else {
                        fout[(size_t)m * Nout + j] = v;
                    }
                }
            }
    }
}

// ---------------------------------------------------------------------------
// K2: MFMA flash attention (validated r6) — epilogue now emits bf16
// ---------------------------------------------------------------------------
__global__ __launch_bounds__(256) void attn_mfma_k(
    const u16* __restrict__ qb, const u16* __restrict__ kb,
    const u16* __restrict__ vtb, const int* __restrict__ lengths,
    u16* __restrict__ outb)
{
    __shared__ __align__(16) char QsB[8192];   // [64 q][64 d] bf16, swizzled
    __shared__ __align__(16) char KsB[8192];   // [64 k][64 d]
    __shared__ __align__(16) char VtB[8192];   // [64 d][64 k]
    __shared__ __align__(16) char PsB[8192];   // [64 q][64 k]

    const int tid = threadIdx.x;
    const int qt = blockIdx.x;
    const int bh = blockIdx.y;
    const int b  = bh >> 2;
    const int len = lengths[b];
    const int w  = tid >> 6;
    const int l  = tid & 63;
    const int g  = l >> 4;
    const int li = l & 15;

    for (int c = tid; c < 512; c += 256) {
        const int row = c >> 3, blk = c & 7;
        const uint4 v = *(const uint4*)(qb + ((size_t)bh * Nn + qt * 64 + row) * 64 + blk * 8);
        *(uint4*)(QsB + SWZB(row, blk * 8)) = v;
    }
    __syncthreads();
    bf16x8 aq[2];
    #pragma unroll
    for (int ks = 0; ks < 2; ks++)
        aq[ks] = *(const bf16x8*)(QsB + SWZB(16 * w + li, 32 * ks + 8 * g));

    f32x4 oacc[4];
    #pragma unroll
    for (int df = 0; df < 4; df++) oacc[df] = f32x4{0.f, 0.f, 0.f, 0.f};
    float m_run[4], l_run[4];
    #pragma unroll
    for (int r = 0; r < 4; r++) { m_run[r] = NEG; l_run[r] = 0.f; }

    const int ktmax = (len + 63) >> 6;
    for (int kt = 0; kt < ktmax; ++kt) {
        __syncthreads();
        for (int c = tid; c < 512; c += 256) {
            const int row = c >> 3, blk = c & 7;
            const uint4 v = *(const uint4*)(kb + ((size_t)bh * Nn + kt * 64 + row) * 64 + blk * 8);
            *(uint4*)(KsB + SWZB(row, blk * 8)) = v;
        }
        for (int c = tid; c < 512; c += 256) {
            const int row = c >> 3, blk = c & 7;
            const uint4 v = *(const uint4*)(vtb + ((size_t)bh * 64 + row) * Nn + kt * 64 + blk * 8);
            *(uint4*)(VtB + SWZB(row, blk * 8)) = v;
        }
        __syncthreads();

        f32x4 s[4];
        #pragma unroll
        for (int cf = 0; cf < 4; cf++) {
            f32x4 z = f32x4{0.f, 0.f, 0.f, 0.f};
            #pragma unroll
            for (int ks = 0; ks < 2; ks++) {
                const bf16x8 bk = *(const bf16x8*)(KsB + SWZB(16 * cf + li, 32 * ks + 8 * g));
                z = __builtin_amdgcn_mfma_f32_16x16x32_bf16(aq[ks], bk, z, 0, 0, 0);
            }
            s[cf] = z;
        }
        float mt[4];
        #pragma unroll
        for (int r = 0; r < 4; r++) mt[r] = NEG;
        #pragma unroll
        for (int cf = 0; cf < 4; cf++) {
            const bool ok = (kt * 64 + 16 * cf + li) < len;
            #pragma unroll
            for (int r = 0; r < 4; r++) {
                const float v = ok ? s[cf][r] * 0.125f : NEG;
                s[cf][r] = v;
                mt[r] = fmaxf(mt[r], v);
            }
        }
        #pragma unroll
        for (int off = 1; off < 16; off <<= 1)
            #pragma unroll
            for (int r = 0; r < 4; r++) mt[r] = fmaxf(mt[r], __shfl_xor(mt[r], off));

        float f[4], sum[4];
        #pragma unroll
        for (int r = 0; r < 4; r++) {
            const float mn = fmaxf(m_run[r], mt[r]);
            f[r] = __expf(m_run[r] - mn);
            m_run[r] = mn;
            sum[r] = 0.f;
        }
        #pragma unroll
        for (int cf = 0; cf < 4; cf++)
            #pragma unroll
            for (int r = 0; r < 4; r++) {
                const float p = __expf(s[cf][r] - m_run[r]);
                sum[r] += p;
                const int row = 16 * w + 4 * g + r;
                *(u16*)(PsB + SWZB(row, 16 * cf + li)) = f2bf(p);
            }
        #pragma unroll
        for (int off = 1; off < 16; off <<= 1)
            #pragma unroll
            for (int r = 0; r < 4; r++) sum[r] += __shfl_xor(sum[r], off);
        #pragma unroll
        for (int r = 0; r < 4; r++) l_run[r] = l_run[r] * f[r] + sum[r];
        #pragma unroll
        for (int df = 0; df < 4; df++)
            #pragma unroll
            for (int r = 0; r < 4; r++) oacc[df][r] *= f[r];
        bf16x8 ap[2];
        #pragma unroll
        for (int ks = 0; ks < 2; ks++)
            ap[ks] = *(const bf16x8*)(PsB + SWZB(16 * w + li, 32 * ks + 8 * g));
        #pragma unroll
        for (int df = 0; df < 4; df++)
            #pragma unroll
            for (int ks = 0; ks < 2; ks++) {
                const bf16x8 bv = *(const bf16x8*)(VtB + SWZB(16 * df + li, 32 * ks + 8 * g));
                oacc[df] = __builtin_amdgcn_mfma_f32_16x16x32_bf16(ap[ks], bv, oacc[df], 0, 0, 0);
            }
    }
    #pragma unroll
    for (int r = 0; r < 4; r++) {
        const float inv = 1.f / l_run[r];
        const int qrow = qt * 64 + 16 * w + 4 * g + r;
        const size_t base = ((size_t)b * Nn + qrow) * Cc + (bh & 3) * 64;
        #pragma unroll
        for (int df = 0; df < 4; df++)
            outb[base + 16 * df + li] = f2bf(oacc[df][r] * inv);
    }
}

// ---------------------------------------------------------------------------
// LayerNorm: MODE 0 -> fp32 + bf16 outputs (ln1); MODE 1 -> bf16 only (ln2)
// ---------------------------------------------------------------------------
template<int MODE>
__global__ __launch_bounds__(256) void ln_k(
    const float* __restrict__ in, const float* __restrict__ w,
    const float* __restrict__ bc, float* __restrict__ outf,
    u16* __restrict__ outb)
{
    const int wave = threadIdx.x >> 6, lane = threadIdx.x & 63;
    const int row = blockIdx.x * 4 + wave;
    const float* p = in + (size_t)row * 256;
    const float v0 = p[lane], v1 = p[lane + 64], v2 = p[lane + 128], v3 = p[lane + 192];
    float s = v0 + v1 + v2 + v3;
    float s2 = v0 * v0 + v1 * v1 + v2 * v2 + v3 * v3;
    #pragma unroll
    for (int off = 32; off > 0; off >>= 1) {
        s  += __shfl_xor(s, off);
        s2 += __shfl_xor(s2, off);
    }
    const float mean = s * (1.f / 256.f);
    const float var  = s2 * (1.f / 256.f) - mean * mean;
    const float rstd = rsqrtf(var + 1e-5f);
    const float o0 = (v0 - mean) * rstd * w[lane]       + bc[lane];
    const float o1 = (v1 - mean) * rstd * w[lane + 64]  + bc[lane + 64];
    const float o2 = (v2 - mean) * rstd * w[lane + 128] + bc[lane + 128];
    const float o3 = (v3 - mean) * rstd * w[lane + 192] + bc[lane + 192];
    if (MODE == 0) {
        float* q = outf + (size_t)row * 256;
        q[lane] = o0; q[lane + 64] = o1; q[lane + 128] = o2; q[lane + 192] = o3;
    }
    u16* qb = outb + (size_t)row * 256;
    qb[lane] = f2bf(o0); qb[lane + 64] = f2bf(o1);
    qb[lane + 128] = f2bf(o2); qb[lane + 192] = f2bf(o3);
}

// ---------------------------------------------------------------------------
// K9: masked sequence softmax (unchanged)
// ---------------------------------------------------------------------------
__global__ __launch_bounds__(256) void smax_k(
    const float* __restrict__ logits, const int* __restrict__ lengths,
    float* __restrict__ outp)
{
    __shared__ float red[8];
    const int bk = blockIdx.x;
    const int b = bk >> 6, kc = bk & 63;
    const int len = lengths[b];
    const int tid = threadIdx.x;
    const int lane = tid & 63, wv = tid >> 6;

    float m = NEG;
    for (int n = tid; n < len; n += 256)
        m = fmaxf(m, logits[((size_t)b * Nn + n) * KK + kc]);
    #pragma unroll
    for (int off = 32; off > 0; off >>= 1) m = fmaxf(m, __shfl_xor(m, off));
    if (lane == 0) red[wv] = m;
    __syncthreads();
    m = fmaxf(fmaxf(red[0], red[1]), fmaxf(red[2], red[3]));

    float s = 0.f;
    for (int n = tid; n < len; n += 256)
        s += __expf(logits[((size_t)b * Nn + n) * KK + kc] - m);
    #pragma unroll
    for (int off = 32; off > 0; off >>= 1) s += __shfl_xor(s, off);
    if (lane == 0) red[4 + wv] = s;
    __syncthreads();
    s = red[4] + red[5] + red[6] + red[7];
    const float inv = 1.f / s;

    for (int n = tid; n < Nn; n += 256) {
        float o = 0.f;
        if (n < len)
            o = __expf(logits[((size_t)b * Nn + n) * KK + kc] - m) * inv;
        outp[((size_t)b * KK + kc) * Nn + n] = o;
    }
}

// ---------------------------------------------------------------------------
extern "C" void kernel_launch(void* const* d_in, const int* in_sizes, int n_in,
                              void* d_out, int out_size, void* d_ws, size_t ws_size,
                              hipStream_t stream)
{
    (void)in_sizes; (void)n_in; (void)out_size; (void)ws_size;
    const float* x      = (const float*)d_in[0];
    const int*   lens   = (const int*)d_in[1];
    const float* WQ     = (const float*)d_in[2];
    const float* WK     = (const float*)d_in[3];
    const float* WV     = (const float*)d_in[4];
    const float* in_w   = (const float*)d_in[5];
    const float* in_b   = (const float*)d_in[6];
    const float* op_w   = (const float*)d_in[7];
    const float* op_b   = (const float*)d_in[8];
    const float* ln1w   = (const float*)d_in[9];
    const float* ln1b   = (const float*)d_in[10];
    const float* ln2w   = (const float*)d_in[11];
    const float* ln2b   = (const float*)d_in[12];
    const float* ff1w   = (const float*)d_in[13];
    const float* ff1b   = (const float*)d_in[14];
    const float* ff2w   = (const float*)d_in[15];
    const float* ff2b   = (const float*)d_in[16];
    const float* prw    = (const float*)d_in[17];
    const float* prb    = (const float*)d_in[18];
    float* out = (float*)d_out;

    // workspace (lifetime-scheduled; peak 88 MB, < proven 97 MB)
    char* ws = (char*)d_ws;
    const size_t MB = 1024 * 1024;
    u16*   xb    = (u16*)(ws + 0);         // [M][256] bf16, 8 MB
    u16*   cwb   = (u16*)(ws +  8 * MB);   // [768][256] 384 KB
    u16*   opwb  = (u16*)(ws +  9 * MB);   // [256][256] 128 KB
    u16*   f1wb  = (u16*)(ws + 10 * MB);   // [512][256] 256 KB
    u16*   f2wb  = (u16*)(ws + 11 * MB);   // [256][512] 256 KB
    u16*   prwb  = (u16*)(ws + 12 * MB);   // [64][256]   32 KB
    u16*   qbuf  = (u16*)(ws + 16 * MB);   // 8 MB
    u16*   kbuf  = (u16*)(ws + 24 * MB);   // 8 MB
    u16*   vtbuf = (u16*)(ws + 32 * MB);   // 8 MB
    u16*   aob   = (u16*)(ws + 40 * MB);   // attn out bf16, 8 MB
    float* y1    = (float*)(ws + 48 * MB); // 16 MB
    float* h1    = (float*)(ws + 64 * MB); // 16 MB (fp32 residual)
    u16*   h1b   = (u16*)(ws + 80 * MB);   // 8 MB
    u16*   ffmid = (u16*)(ws + 16 * MB);   // [M][512] bf16 16 MB (q/k dead)
    float* y2    = (float*)(ws + 32 * MB); // 16 MB (vt/aob dead)
    u16*   h2b   = (u16*)(ws + 16 * MB);   // 8 MB (ffmid dead)
    float* logits= (float*)(ws + 24 * MB); // 4 MB

    xt_k<<<dim3(Nn / 64, Cc / 64, Bb), 256, 0, stream>>>(x, xb);
    combine_w_k<<<768, 256, 0, stream>>>(WQ, WK, WV, in_w, cwb);
    cvt4_k<<<256, 256, 0, stream>>>(op_w, opwb, 256 * 256,
                                    ff1w, f1wb, 512 * 256,
                                    ff2w, f2wb, 256 * 512,
                                    prw,  prwb, 64 * 256);
    gemm_mfma_k<0><<<dim3(Mm / 128, 768 / 64), 256, 0, stream>>>(
        xb, cwb, in_b, nullptr, nullptr, qbuf, kbuf, vtbuf, 768, 256);
    attn_mfma_k<<<dim3(Nn / 64, Bb * Hh), 256, 0, stream>>>(qbuf, kbuf, vtbuf, lens, aob);
    gemm_mfma_k<1><<<dim3(Mm / 128, 256 / 64), 256, 0, stream>>>(
        aob, opwb, op_b, x, y1, nullptr, nullptr, nullptr, 256, 256);
    ln_k<0><<<Mm / 4, 256, 0, stream>>>(y1, ln1w, ln1b, h1, h1b);
    gemm_mfma_k<2><<<dim3(Mm / 128, 512 / 64), 256, 0, stream>>>(
        h1b, f1wb, ff1b, nullptr, nullptr, ffmid, nullptr, nullptr, 512, 256);
    gemm_mfma_k<3><<<dim3(Mm / 128, 256 / 64), 256, 0, stream>>>(
        ffmid, f2wb, ff2b, h1, y2, nullptr, nullptr, nullptr, 256, 512);
    ln_k<1><<<Mm / 4, 256, 0, stream>>>(y2, ln2w, ln2b, nullptr, h2b);
    gemm_mfma_k<4><<<dim3(Mm / 128, 64 / 64), 256, 0, stream>>>(
        h2b, prwb, prb, nullptr, logits, nullptr, nullptr, nullptr, 64, 256);
    smax_k<<<Bb * KK, 256, 0, stream>>>(logits, lens, out);
}

// Round 11
// 313.330 us; speedup vs baseline: 2.6667x; 1.0479x over previous
//
#include <hip/hip_runtime.h>
#include <math.h>

// Problem constants (match reference)
constexpr int Bb = 8, Cc = 256, Nn = 2048, Hh = 4, HD = 64, KK = 64;
constexpr int Mm = Bb * Nn;  // 16384
constexpr float NEG = -1e30f;

typedef unsigned short u16;
typedef unsigned int u32;
typedef __attribute__((ext_vector_type(8))) short bf16x8;   // 8 bf16 = 4 VGPRs
typedef __attribute__((ext_vector_type(4))) float f32x4;    // MFMA C/D

static __device__ __forceinline__ u16 f2bf(float x) {       // fp32 -> bf16 RNE
    union { float f; unsigned u; } v; v.f = x;
    const unsigned r = v.u + 0x7FFFu + ((v.u >> 16) & 1u);
    return (u16)(r >> 16);
}
static __device__ __forceinline__ u32 pk2(float a, float b) { // 2xbf16 LE pack
    return (u32)f2bf(a) | ((u32)f2bf(b) << 16);
}

// XOR-swizzled byte offset in a [rows][64 bf16] LDS tile (validated r6/r9: 0 conflicts)
#define SWZB(row, col) ((((row) * 128) + ((col) * 2)) ^ (((row) & 7) << 4))

// ---------------------------------------------------------------------------
// xt_k: x [B,C,N] fp32 -> xb [B,N,C] bf16  (64x64 LDS-tiled transpose)
// ---------------------------------------------------------------------------
__global__ __launch_bounds__(256) void xt_k(
    const float* __restrict__ x, u16* __restrict__ xb)
{
    __shared__ float Ts[64][65];
    const int tid = threadIdx.x;
    const int n0 = blockIdx.x * 64, c0 = blockIdx.y * 64, b = blockIdx.z;
    for (int c = tid; c < 1024; c += 256) {
        const int row = c >> 4, col = (c & 15) * 4;
        const float4 v = *(const float4*)(x + ((size_t)b * Cc + c0 + row) * Nn + n0 + col);
        Ts[row][col + 0] = v.x; Ts[row][col + 1] = v.y;
        Ts[row][col + 2] = v.z; Ts[row][col + 3] = v.w;
    }
    __syncthreads();
    for (int c = tid; c < 1024; c += 256) {
        const int nr = c >> 4, cc = (c & 15) * 4;
        const ushort4 o = make_ushort4(f2bf(Ts[cc + 0][nr]), f2bf(Ts[cc + 1][nr]),
                                       f2bf(Ts[cc + 2][nr]), f2bf(Ts[cc + 3][nr]));
        *(ushort4*)(xb + ((size_t)b * Nn + n0 + nr) * Cc + c0 + cc) = o;
    }
}

// ---------------------------------------------------------------------------
// K0: combine projection weights -> bf16 cwb[768][256]
// ---------------------------------------------------------------------------
__global__ __launch_bounds__(256) void combine_w_k(
    const float* __restrict__ WQ, const float* __restrict__ WK,
    const float* __restrict__ WV, const float* __restrict__ inw,
    u16* __restrict__ cwb)
{
    __shared__ float ssub[256];
    const int row = blockIdx.x;          // 0..767
    const int part = row >> 8;
    const float* Wsrc = (part == 0) ? WQ : (part == 1) ? WK : WV;
    const int tid = threadIdx.x;
    ssub[tid] = inw[(size_t)row * 256 + tid];
    __syncthreads();
    float acc = 0.f;
    for (int c = 0; c < 256; c++)
        acc += Wsrc[(size_t)tid * 256 + c] * ssub[c];
    cwb[(size_t)row * 256 + tid] = f2bf(acc);
}

// ---------------------------------------------------------------------------
// cvt4_k: four fp32->bf16 weight conversions in one launch
// ---------------------------------------------------------------------------
__global__ __launch_bounds__(256) void cvt4_k(
    const float* __restrict__ s0, u16* __restrict__ d0, int c0_,
    const float* __restrict__ s1, u16* __restrict__ d1, int c1_,
    const float* __restrict__ s2, u16* __restrict__ d2, int c2_,
    const float* __restrict__ s3, u16* __restrict__ d3, int c3_)
{
    const int q0 = c0_ >> 2, q1 = c1_ >> 2, q2 = c2_ >> 2, q3 = c3_ >> 2;
    const int total = q0 + q1 + q2 + q3;
    for (int i = blockIdx.x * 256 + threadIdx.x; i < total; i += gridDim.x * 256) {
        const float* s; u16* d; int idx = i;
        if (idx < q0)            { s = s0; d = d0; }
        else if ((idx -= q0) < q1) { s = s1; d = d1; }
        else if ((idx -= q1) < q2) { s = s2; d = d2; }
        else { idx -= q2;          s = s3; d = d3; }
        const float4 v = ((const float4*)s)[idx];
        ((ushort4*)d)[idx] = make_ushort4(f2bf(v.x), f2bf(v.y), f2bf(v.z), f2bf(v.w));
    }
}

// ---------------------------------------------------------------------------
// gemm_mfma_k: D[m,j] = sum_k A[m,k]*W[j,k] + bias[j]  (bf16 in, fp32 acc)
// BM=128 BN=64 BK=64, 256 thr = 4 waves (2Mx2N), wave tile 64x32.
// EPI: 0 qkv-split (Q scaled by 0.125 for attn; Q/K bf16 [bh][n][d], V^T [bh][d][n])
//      1 +bias +x[b,j,n] residual -> fp32      (out_proj)
//      2 +bias, GELU -> bf16                   (ff1)
//      3 +bias +res[m,j] fp32 residual -> fp32 (ff2)
//      4 +bias -> fp32                         (proj)
// ---------------------------------------------------------------------------
template<int EPI>
__global__ __launch_bounds__(256) void gemm_mfma_k(
    const u16* __restrict__ A, const u16* __restrict__ W,
    const float* __restrict__ bias, const float* __restrict__ res,
    float* __restrict__ fout, u16* __restrict__ bout,
    u16* __restrict__ kout, u16* __restrict__ vtout,
    int Nout, int Kdim)
{
    __shared__ __align__(16) char AsB[128 * 128];  // 128 rows x 64 bf16, swizzled
    __shared__ __align__(16) char WsB[64 * 128];   // 64 rows x 64 bf16

    const int tid = threadIdx.x;
    const int m0 = blockIdx.x * 128, n0 = blockIdx.y * 64;
    const int w = tid >> 6, l = tid & 63, g = l >> 4, li = l & 15;
    const int wm = w >> 1, wn = w & 1;

    f32x4 acc[4][2];
    #pragma unroll
    for (int mf = 0; mf < 4; mf++)
        #pragma unroll
        for (int nf = 0; nf < 2; nf++) acc[mf][nf] = f32x4{0.f, 0.f, 0.f, 0.f};

    for (int kt = 0; kt < Kdim; kt += 64) {
        __syncthreads();   // prev k-step frag reads complete
        for (int c = tid; c < 1024; c += 256) {       // stage A 128x64
            const int row = c >> 3, blk = c & 7;
            const uint4 v = *(const uint4*)(A + (size_t)(m0 + row) * Kdim + kt + blk * 8);
            *(uint4*)(AsB + SWZB(row, blk * 8)) = v;
        }
        for (int c = tid; c < 512; c += 256) {        // stage W 64x64
            const int row = c >> 3, blk = c & 7;
            const uint4 v = *(const uint4*)(W + (size_t)(n0 + row) * Kdim + kt + blk * 8);
            *(uint4*)(WsB + SWZB(row, blk * 8)) = v;
        }
        __syncthreads();
        #pragma unroll
        for (int ks = 0; ks < 2; ks++) {
            bf16x8 af[4], bfr[2];
            #pragma unroll
            for (int mf = 0; mf < 4; mf++)
                af[mf] = *(const bf16x8*)(AsB + SWZB(wm * 64 + mf * 16 + li, ks * 32 + 8 * g));
            #pragma unroll
            for (int nf = 0; nf < 2; nf++)
                bfr[nf] = *(const bf16x8*)(WsB + SWZB(wn * 32 + nf * 16 + li, ks * 32 + 8 * g));
            #pragma unroll
            for (int mf = 0; mf < 4; mf++)
                #pragma unroll
                for (int nf = 0; nf < 2; nf++)
                    acc[mf][nf] = __builtin_amdgcn_mfma_f32_16x16x32_bf16(af[mf], bfr[nf], acc[mf][nf], 0, 0, 0);
        }
    }

    // ---------------- epilogue ----------------
    if (EPI == 0) {
        const int part = n0 >> 8;            // 0=q 1=k 2=v
        const int h    = (n0 >> 6) & 3;
        const int b    = m0 >> 11;
        const int bh   = b * 4 + h;
        const float sc = (part == 0) ? 0.125f : 1.0f;   // fold attn scale into Q
        #pragma unroll
        for (int mf = 0; mf < 4; mf++)
            #pragma unroll
            for (int nf = 0; nf < 2; nf++) {
                const int d  = wn * 32 + nf * 16 + li;          // 0..63 head dim
                const float bv = bias[n0 + d];
                const int nr0 = (m0 & (Nn - 1)) + wm * 64 + mf * 16 + 4 * g;
                if (part < 2) {
                    u16* dst = (part == 0) ? bout : kout;
                    #pragma unroll
                    for (int r = 0; r < 4; r++)
                        dst[((size_t)bh * Nn + nr0 + r) * 64 + d] = f2bf((acc[mf][nf][r] + bv) * sc);
                } else {
                    const ushort4 o = make_ushort4(
                        f2bf(acc[mf][nf][0] + bv), f2bf(acc[mf][nf][1] + bv),
                        f2bf(acc[mf][nf][2] + bv), f2bf(acc[mf][nf][3] + bv));
                    *(ushort4*)(vtout + ((size_t)bh * 64 + d) * Nn + nr0) = o;
                }
            }
    } else {
        #pragma unroll
        for (int mf = 0; mf < 4; mf++)
            #pragma unroll
            for (int nf = 0; nf < 2; nf++) {
                const int j = n0 + wn * 32 + nf * 16 + li;
                const float bv = bias[j];
                #pragma unroll
                for (int r = 0; r < 4; r++) {
                    const int m = m0 + wm * 64 + mf * 16 + 4 * g + r;
                    float v = acc[mf][nf][r] + bv;
                    if (EPI == 1) {
                        v += res[((size_t)(m >> 11) * Cc + j) * Nn + (m & (Nn - 1))];
                        fout[(size_t)m * Nout + j] = v;
                    } else if (EPI == 2) {
                        v = 0.5f * v * (1.0f + erff(v * 0.70710678118f));
                        bout[(size_t)m * Nout + j] = f2bf(v);
                    } else if (EPI == 3) {
                        v += res[(size_t)m * Nout + j];
                        fout[(size_t)m * Nout + j] = v;
                    } else {
                        fout[(size_t)m * Nout + j] = v;
                    }
                }
            }
    }
}

// ---------------------------------------------------------------------------
// K2: MFMA flash attention, SWAPPED QK^T (S^T = mfma(K,Q)) so each lane owns
// one query column: softmax reduce = 15 reg fmax + 2 shfl; P packs into
// 4x ds_write_b64 and feeds PV's B-operand directly (O^T = mfma(V^T, P^T)).
// Q pre-scaled by 0.125 in gemm_mfma_k<0>. Mask hoisted to last tile only.
// ---------------------------------------------------------------------------
__global__ __launch_bounds__(256) void attn_mfma_k(
    const u16* __restrict__ qb, const u16* __restrict__ kb,
    const u16* __restrict__ vtb, const int* __restrict__ lengths,
    u16* __restrict__ outb)
{
    __shared__ __align__(16) char QsB[8192];   // [64 q][64 d] bf16, swizzled
    __shared__ __align__(16) char KsB[8192];   // [64 k][64 d]
    __shared__ __align__(16) char VtB[8192];   // [64 d][64 k]
    __shared__ __align__(16) char PtB[8192];   // [64 q][64 k]  (wave-private rows)

    const int tid = threadIdx.x;
    const int qt = blockIdx.x;
    const int bh = blockIdx.y;
    const int b  = bh >> 2;
    const int len = lengths[b];
    const int w  = tid >> 6;
    const int l  = tid & 63;
    const int g  = l >> 4;
    const int li = l & 15;

    for (int c = tid; c < 512; c += 256) {     // stage Q tile
        const int row = c >> 3, blk = c & 7;
        const uint4 v = *(const uint4*)(qb + ((size_t)bh * Nn + qt * 64 + row) * 64 + blk * 8);
        *(uint4*)(QsB + SWZB(row, blk * 8)) = v;
    }
    __syncthreads();
    // Q as B-operand fragment: col = query li (wave rows 16w..16w+15), k = dim
    bf16x8 bq[2];
    #pragma unroll
    for (int ks = 0; ks < 2; ks++)
        bq[ks] = *(const bf16x8*)(QsB + SWZB(16 * w + li, 32 * ks + 8 * g));

    // O^T accumulator: oacc[df][r] = O[query li][dim 16df+4g+r]
    f32x4 oacc[4];
    #pragma unroll
    for (int df = 0; df < 4; df++) oacc[df] = f32x4{0.f, 0.f, 0.f, 0.f};
    float m_run = NEG, l_run = 0.f;            // per-lane scalars (one query)

    const int ktmax = (len + 63) >> 6;
    for (int kt = 0; kt < ktmax; ++kt) {
        __syncthreads();   // prev tile's K/V frag reads complete
        for (int c = tid; c < 512; c += 256) {      // K tile [key][dim]
            const int row = c >> 3, blk = c & 7;
            const uint4 v = *(const uint4*)(kb + ((size_t)bh * Nn + kt * 64 + row) * 64 + blk * 8);
            *(uint4*)(KsB + SWZB(row, blk * 8)) = v;
        }
        for (int c = tid; c < 512; c += 256) {      // V^T tile [dim][key]
            const int row = c >> 3, blk = c & 7;
            const uint4 v = *(const uint4*)(vtb + ((size_t)bh * 64 + row) * Nn + kt * 64 + blk * 8);
            *(uint4*)(VtB + SWZB(row, blk * 8)) = v;
        }
        __syncthreads();

        // S^T[key][query] = mfma(A=K, B=Q): s[cf][r] = S^T[16cf+4g+r][li]
        f32x4 s[4];
        #pragma unroll
        for (int cf = 0; cf < 4; cf++) {
            f32x4 z = f32x4{0.f, 0.f, 0.f, 0.f};
            #pragma unroll
            for (int ks = 0; ks < 2; ks++) {
                const bf16x8 ak = *(const bf16x8*)(KsB + SWZB(16 * cf + li, 32 * ks + 8 * g));
                z = __builtin_amdgcn_mfma_f32_16x16x32_bf16(ak, bq[ks], z, 0, 0, 0);
            }
            s[cf] = z;
        }
        // key mask — only the (at most one) partial tile; wave-uniform branch
        if (kt * 64 + 64 > len) {
            #pragma unroll
            for (int cf = 0; cf < 4; cf++)
                #pragma unroll
                for (int r = 0; r < 4; r++)
                    if (kt * 64 + 16 * cf + 4 * g + r >= len) s[cf][r] = NEG;
        }
        // query-row max: 15 in-register fmax + 2 shfl (g-groups share query li)
        float mt = s[0][0];
        #pragma unroll
        for (int cf = 0; cf < 4; cf++)
            #pragma unroll
            for (int r = 0; r < 4; r++) mt = fmaxf(mt, s[cf][r]);
        mt = fmaxf(mt, __shfl_xor(mt, 16));
        mt = fmaxf(mt, __shfl_xor(mt, 32));
        const float mn = fmaxf(m_run, mt);
        const float f = __expf(m_run - mn);
        m_run = mn;
        // P = exp(S - m): pack consecutive keys to bf16 pairs, sum locally
        float sum = 0.f;
        u32 pw[4][2];
        #pragma unroll
        for (int cf = 0; cf < 4; cf++) {
            const float p0 = __expf(s[cf][0] - mn);
            const float p1 = __expf(s[cf][1] - mn);
            const float p2 = __expf(s[cf][2] - mn);
            const float p3 = __expf(s[cf][3] - mn);
            sum += (p0 + p1) + (p2 + p3);
            pw[cf][0] = pk2(p0, p1);
            pw[cf][1] = pk2(p2, p3);
        }
        sum += __shfl_xor(sum, 16);
        sum += __shfl_xor(sum, 32);
        l_run = l_run * f + sum;
        // write P^T rows (wave-private): 4 x b64, keys 16cf+4g..+3 of query li
        #pragma unroll
        for (int cf = 0; cf < 4; cf++) {
            uint2 pr; pr.x = pw[cf][0]; pr.y = pw[cf][1];
            *(uint2*)(PtB + SWZB(16 * w + li, 16 * cf + 4 * g)) = pr;
        }
        // rescale O^T
        #pragma unroll
        for (int df = 0; df < 4; df++)
            #pragma unroll
            for (int r = 0; r < 4; r++) oacc[df][r] *= f;
        // O^T += V^T · P^T  (A = V^T rows=dims, B = P^T col=query)
        bf16x8 bp[2];
        #pragma unroll
        for (int ks = 0; ks < 2; ks++)
            bp[ks] = *(const bf16x8*)(PtB + SWZB(16 * w + li, 32 * ks + 8 * g));
        #pragma unroll
        for (int df = 0; df < 4; df++)
            #pragma unroll
            for (int ks = 0; ks < 2; ks++) {
                const bf16x8 av = *(const bf16x8*)(VtB + SWZB(16 * df + li, 32 * ks + 8 * g));
                oacc[df] = __builtin_amdgcn_mfma_f32_16x16x32_bf16(av, bp[ks], oacc[df], 0, 0, 0);
            }
    }
    // epilogue: query = qt*64+16w+li owns dims 16df+4g+r -> 4x ushort4 stores
    const float inv = 1.f / l_run;
    const size_t base = ((size_t)b * Nn + qt * 64 + 16 * w + li) * Cc + (bh & 3) * 64;
    #pragma unroll
    for (int df = 0; df < 4; df++) {
        const ushort4 o = make_ushort4(f2bf(oacc[df][0] * inv), f2bf(oacc[df][1] * inv),
                                       f2bf(oacc[df][2] * inv), f2bf(oacc[df][3] * inv));
        *(ushort4*)(outb + base + 16 * df + 4 * g) = o;
    }
}

// ---------------------------------------------------------------------------
// LayerNorm: MODE 0 -> fp32 + bf16 outputs (ln1); MODE 1 -> bf16 only (ln2)
// ---------------------------------------------------------------------------
template<int MODE>
__global__ __launch_bounds__(256) void ln_k(
    const float* __restrict__ in, const float* __restrict__ w,
    const float* __restrict__ bc, float* __restrict__ outf,
    u16* __restrict__ outb)
{
    const int wave = threadIdx.x >> 6, lane = threadIdx.x & 63;
    const int row = blockIdx.x * 4 + wave;
    const float* p = in + (size_t)row * 256;
    const float v0 = p[lane], v1 = p[lane + 64], v2 = p[lane + 128], v3 = p[lane + 192];
    float s = v0 + v1 + v2 + v3;
    float s2 = v0 * v0 + v1 * v1 + v2 * v2 + v3 * v3;
    #pragma unroll
    for (int off = 32; off > 0; off >>= 1) {
        s  += __shfl_xor(s, off);
        s2 += __shfl_xor(s2, off);
    }
    const float mean = s * (1.f / 256.f);
    const float var  = s2 * (1.f / 256.f) - mean * mean;
    const float rstd = rsqrtf(var + 1e-5f);
    const float o0 = (v0 - mean) * rstd * w[lane]       + bc[lane];
    const float o1 = (v1 - mean) * rstd * w[lane + 64]  + bc[lane + 64];
    const float o2 = (v2 - mean) * rstd * w[lane + 128] + bc[lane + 128];
    const float o3 = (v3 - mean) * rstd * w[lane + 192] + bc[lane + 192];
    if (MODE == 0) {
        float* q = outf + (size_t)row * 256;
        q[lane] = o0; q[lane + 64] = o1; q[lane + 128] = o2; q[lane + 192] = o3;
    }
    u16* qb = outb + (size_t)row * 256;
    qb[lane] = f2bf(o0); qb[lane + 64] = f2bf(o1);
    qb[lane + 128] = f2bf(o2); qb[lane + 192] = f2bf(o3);
}

// ---------------------------------------------------------------------------
// K9: masked sequence softmax (unchanged)
// ---------------------------------------------------------------------------
__global__ __launch_bounds__(256) void smax_k(
    const float* __restrict__ logits, const int* __restrict__ lengths,
    float* __restrict__ outp)
{
    __shared__ float red[8];
    const int bk = blockIdx.x;
    const int b = bk >> 6, kc = bk & 63;
    const int len = lengths[b];
    const int tid = threadIdx.x;
    const int lane = tid & 63, wv = tid >> 6;

    float m = NEG;
    for (int n = tid; n < len; n += 256)
        m = fmaxf(m, logits[((size_t)b * Nn + n) * KK + kc]);
    #pragma unroll
    for (int off = 32; off > 0; off >>= 1) m = fmaxf(m, __shfl_xor(m, off));
    if (lane == 0) red[wv] = m;
    __syncthreads();
    m = fmaxf(fmaxf(red[0], red[1]), fmaxf(red[2], red[3]));

    float s = 0.f;
    for (int n = tid; n < len; n += 256)
        s += __expf(logits[((size_t)b * Nn + n) * KK + kc] - m);
    #pragma unroll
    for (int off = 32; off > 0; off >>= 1) s += __shfl_xor(s, off);
    if (lane == 0) red[4 + wv] = s;
    __syncthreads();
    s = red[4] + red[5] + red[6] + red[7];
    const float inv = 1.f / s;

    for (int n = tid; n < Nn; n += 256) {
        float o = 0.f;
        if (n < len)
            o = __expf(logits[((size_t)b * Nn + n) * KK + kc] - m) * inv;
        outp[((size_t)b * KK + kc) * Nn + n] = o;
    }
}

// ---------------------------------------------------------------------------
extern "C" void kernel_launch(void* const* d_in, const int* in_sizes, int n_in,
                              void* d_out, int out_size, void* d_ws, size_t ws_size,
                              hipStream_t stream)
{
    (void)in_sizes; (void)n_in; (void)out_size; (void)ws_size;
    const float* x      = (const float*)d_in[0];
    const int*   lens   = (const int*)d_in[1];
    const float* WQ     = (const float*)d_in[2];
    const float* WK     = (const float*)d_in[3];
    const float* WV     = (const float*)d_in[4];
    const float* in_w   = (const float*)d_in[5];
    const float* in_b   = (const float*)d_in[6];
    const float* op_w   = (const float*)d_in[7];
    const float* op_b   = (const float*)d_in[8];
    const float* ln1w   = (const float*)d_in[9];
    const float* ln1b   = (const float*)d_in[10];
    const float* ln2w   = (const float*)d_in[11];
    const float* ln2b   = (const float*)d_in[12];
    const float* ff1w   = (const float*)d_in[13];
    const float* ff1b   = (const float*)d_in[14];
    const float* ff2w   = (const float*)d_in[15];
    const float* ff2b   = (const float*)d_in[16];
    const float* prw    = (const float*)d_in[17];
    const float* prb    = (const float*)d_in[18];
    float* out = (float*)d_out;

    // workspace (lifetime-scheduled; peak 88 MB, < proven 97 MB)
    char* ws = (char*)d_ws;
    const size_t MB = 1024 * 1024;
    u16*   xb    = (u16*)(ws + 0);         // [M][256] bf16, 8 MB
    u16*   cwb   = (u16*)(ws +  8 * MB);   // [768][256] 384 KB
    u16*   opwb  = (u16*)(ws +  9 * MB);   // [256][256] 128 KB
    u16*   f1wb  = (u16*)(ws + 10 * MB);   // [512][256] 256 KB
    u16*   f2wb  = (u16*)(ws + 11 * MB);   // [256][512] 256 KB
    u16*   prwb  = (u16*)(ws + 12 * MB);   // [64][256]   32 KB
    u16*   qbuf  = (u16*)(ws + 16 * MB);   // 8 MB
    u16*   kbuf  = (u16*)(ws + 24 * MB);   // 8 MB
    u16*   vtbuf = (u16*)(ws + 32 * MB);   // 8 MB
    u16*   aob   = (u16*)(ws + 40 * MB);   // attn out bf16, 8 MB
    float* y1    = (float*)(ws + 48 * MB); // 16 MB
    float* h1    = (float*)(ws + 64 * MB); // 16 MB (fp32 residual)
    u16*   h1b   = (u16*)(ws + 80 * MB);   // 8 MB
    u16*   ffmid = (u16*)(ws + 16 * MB);   // [M][512] bf16 16 MB (q/k dead)
    float* y2    = (float*)(ws + 32 * MB); // 16 MB (vt/aob dead)
    u16*   h2b   = (u16*)(ws + 16 * MB);   // 8 MB (ffmid dead)
    float* logits= (float*)(ws + 24 * MB); // 4 MB

    xt_k<<<dim3(Nn / 64, Cc / 64, Bb), 256, 0, stream>>>(x, xb);
    combine_w_k<<<768, 256, 0, stream>>>(WQ, WK, WV, in_w, cwb);
    cvt4_k<<<256, 256, 0, stream>>>(op_w, opwb, 256 * 256,
                                    ff1w, f1wb, 512 * 256,
                                    ff2w, f2wb, 256 * 512,
                                    prw,  prwb, 64 * 256);
    gemm_mfma_k<0><<<dim3(Mm / 128, 768 / 64), 256, 0, stream>>>(
        xb, cwb, in_b, nullptr, nullptr, qbuf, kbuf, vtbuf, 768, 256);
    attn_mfma_k<<<dim3(Nn / 64, Bb * Hh), 256, 0, stream>>>(qbuf, kbuf, vtbuf, lens, aob);
    gemm_mfma_k<1><<<dim3(Mm / 128, 256 / 64), 256, 0, stream>>>(
        aob, opwb, op_b, x, y1, nullptr, nullptr, nullptr, 256, 256);
    ln_k<0><<<Mm / 4, 256, 0, stream>>>(y1, ln1w, ln1b, h1, h1b);
    gemm_mfma_k<2><<<dim3(Mm / 128, 512 / 64), 256, 0, stream>>>(
        h1b, f1wb, ff1b, nullptr, nullptr, ffmid, nullptr, nullptr, 512, 256);
    gemm_mfma_k<3><<<dim3(Mm / 128, 256 / 64), 256, 0, stream>>>(
        ffmid, f2wb, ff2b, h1, y2, nullptr, nullptr, nullptr, 256, 512);
    ln_k<1><<<Mm / 4, 256, 0, stream>>>(y2, ln2w, ln2b, nullptr, h2b);
    gemm_mfma_k<4><<<dim3(Mm / 128, 64 / 64), 256, 0, stream>>>(
        h2b, prwb, prb, nullptr, logits, nullptr, nullptr, nullptr, 64, 256);
    smax_k<<<Bb * KK, 256, 0, stream>>>(logits, lens, out);
}

// Round 12
// 302.298 us; speedup vs baseline: 2.7640x; 1.0365x over previous
//
#include <hip/hip_runtime.h>
#include <math.h>

// Problem constants (match reference)
constexpr int Bb = 8, Cc = 256, Nn = 2048, Hh = 4, HD = 64, KK = 64;
constexpr int Mm = Bb * Nn;  // 16384
constexpr float NEG = -1e30f;

typedef unsigned short u16;
typedef unsigned int u32;
typedef __attribute__((ext_vector_type(8))) short bf16x8;   // 8 bf16 = 4 VGPRs
typedef __attribute__((ext_vector_type(4))) float f32x4;    // MFMA C/D

static __device__ __forceinline__ u16 f2bf(float x) {       // fp32 -> bf16 RNE
    union { float f; unsigned u; } v; v.f = x;
    const unsigned r = v.u + 0x7FFFu + ((v.u >> 16) & 1u);
    return (u16)(r >> 16);
}
static __device__ __forceinline__ u32 pk2(float a, float b) { // 2xbf16 LE pack
    return (u32)f2bf(a) | ((u32)f2bf(b) << 16);
}

// XOR-swizzled byte offset in a [rows][64 bf16] LDS tile (validated r6/r9: 0 conflicts)
#define SWZB(row, col) ((((row) * 128) + ((col) * 2)) ^ (((row) & 7) << 4))

// ---------------------------------------------------------------------------
// xt_k: x [B,C,N] fp32 -> xb [B,N,C] bf16  (64x64 LDS-tiled transpose)
// ---------------------------------------------------------------------------
__global__ __launch_bounds__(256) void xt_k(
    const float* __restrict__ x, u16* __restrict__ xb)
{
    __shared__ float Ts[64][65];
    const int tid = threadIdx.x;
    const int n0 = blockIdx.x * 64, c0 = blockIdx.y * 64, b = blockIdx.z;
    for (int c = tid; c < 1024; c += 256) {
        const int row = c >> 4, col = (c & 15) * 4;
        const float4 v = *(const float4*)(x + ((size_t)b * Cc + c0 + row) * Nn + n0 + col);
        Ts[row][col + 0] = v.x; Ts[row][col + 1] = v.y;
        Ts[row][col + 2] = v.z; Ts[row][col + 3] = v.w;
    }
    __syncthreads();
    for (int c = tid; c < 1024; c += 256) {
        const int nr = c >> 4, cc = (c & 15) * 4;
        const ushort4 o = make_ushort4(f2bf(Ts[cc + 0][nr]), f2bf(Ts[cc + 1][nr]),
                                       f2bf(Ts[cc + 2][nr]), f2bf(Ts[cc + 3][nr]));
        *(ushort4*)(xb + ((size_t)b * Nn + n0 + nr) * Cc + c0 + cc) = o;
    }
}

// ---------------------------------------------------------------------------
// K0: combine projection weights -> bf16 cwb[768][256]
// ---------------------------------------------------------------------------
__global__ __launch_bounds__(256) void combine_w_k(
    const float* __restrict__ WQ, const float* __restrict__ WK,
    const float* __restrict__ WV, const float* __restrict__ inw,
    u16* __restrict__ cwb)
{
    __shared__ float ssub[256];
    const int row = blockIdx.x;          // 0..767
    const int part = row >> 8;
    const float* Wsrc = (part == 0) ? WQ : (part == 1) ? WK : WV;
    const int tid = threadIdx.x;
    ssub[tid] = inw[(size_t)row * 256 + tid];
    __syncthreads();
    float acc = 0.f;
    for (int c = 0; c < 256; c++)
        acc += Wsrc[(size_t)tid * 256 + c] * ssub[c];
    cwb[(size_t)row * 256 + tid] = f2bf(acc);
}

// ---------------------------------------------------------------------------
// cvt4_k: four fp32->bf16 weight conversions in one launch
// ---------------------------------------------------------------------------
__global__ __launch_bounds__(256) void cvt4_k(
    const float* __restrict__ s0, u16* __restrict__ d0, int c0_,
    const float* __restrict__ s1, u16* __restrict__ d1, int c1_,
    const float* __restrict__ s2, u16* __restrict__ d2, int c2_,
    const float* __restrict__ s3, u16* __restrict__ d3, int c3_)
{
    const int q0 = c0_ >> 2, q1 = c1_ >> 2, q2 = c2_ >> 2, q3 = c3_ >> 2;
    const int total = q0 + q1 + q2 + q3;
    for (int i = blockIdx.x * 256 + threadIdx.x; i < total; i += gridDim.x * 256) {
        const float* s; u16* d; int idx = i;
        if (idx < q0)            { s = s0; d = d0; }
        else if ((idx -= q0) < q1) { s = s1; d = d1; }
        else if ((idx -= q1) < q2) { s = s2; d = d2; }
        else { idx -= q2;          s = s3; d = d3; }
        const float4 v = ((const float4*)s)[idx];
        ((ushort4*)d)[idx] = make_ushort4(f2bf(v.x), f2bf(v.y), f2bf(v.z), f2bf(v.w));
    }
}

// ---------------------------------------------------------------------------
// gemm_mfma_k: D[m,j] = sum_k A[m,k]*W[j,k] + bias[j]  (bf16 in, fp32 acc)
// BM=128 BN=64 BK=64, 256 thr = 4 waves (2Mx2N), wave tile 64x32.
// EPI: 0 qkv-split (Q scaled by 0.125 for attn; Q/K bf16 [bh][n][d], V^T [bh][d][n])
//      1 +bias +x[b,j,n] residual -> fp32      (out_proj)
//      2 +bias, GELU -> bf16                   (ff1)
//      3 +bias +res[m,j] fp32 residual -> fp32 (ff2)
//      4 +bias -> fp32                         (proj)
// ---------------------------------------------------------------------------
template<int EPI>
__global__ __launch_bounds__(256) void gemm_mfma_k(
    const u16* __restrict__ A, const u16* __restrict__ W,
    const float* __restrict__ bias, const float* __restrict__ res,
    float* __restrict__ fout, u16* __restrict__ bout,
    u16* __restrict__ kout, u16* __restrict__ vtout,
    int Nout, int Kdim)
{
    __shared__ __align__(16) char AsB[128 * 128];  // 128 rows x 64 bf16, swizzled
    __shared__ __align__(16) char WsB[64 * 128];   // 64 rows x 64 bf16

    const int tid = threadIdx.x;
    const int m0 = blockIdx.x * 128, n0 = blockIdx.y * 64;
    const int w = tid >> 6, l = tid & 63, g = l >> 4, li = l & 15;
    const int wm = w >> 1, wn = w & 1;

    f32x4 acc[4][2];
    #pragma unroll
    for (int mf = 0; mf < 4; mf++)
        #pragma unroll
        for (int nf = 0; nf < 2; nf++) acc[mf][nf] = f32x4{0.f, 0.f, 0.f, 0.f};

    for (int kt = 0; kt < Kdim; kt += 64) {
        __syncthreads();   // prev k-step frag reads complete
        for (int c = tid; c < 1024; c += 256) {       // stage A 128x64
            const int row = c >> 3, blk = c & 7;
            const uint4 v = *(const uint4*)(A + (size_t)(m0 + row) * Kdim + kt + blk * 8);
            *(uint4*)(AsB + SWZB(row, blk * 8)) = v;
        }
        for (int c = tid; c < 512; c += 256) {        // stage W 64x64
            const int row = c >> 3, blk = c & 7;
            const uint4 v = *(const uint4*)(W + (size_t)(n0 + row) * Kdim + kt + blk * 8);
            *(uint4*)(WsB + SWZB(row, blk * 8)) = v;
        }
        __syncthreads();
        #pragma unroll
        for (int ks = 0; ks < 2; ks++) {
            bf16x8 af[4], bfr[2];
            #pragma unroll
            for (int mf = 0; mf < 4; mf++)
                af[mf] = *(const bf16x8*)(AsB + SWZB(wm * 64 + mf * 16 + li, ks * 32 + 8 * g));
            #pragma unroll
            for (int nf = 0; nf < 2; nf++)
                bfr[nf] = *(const bf16x8*)(WsB + SWZB(wn * 32 + nf * 16 + li, ks * 32 + 8 * g));
            #pragma unroll
            for (int mf = 0; mf < 4; mf++)
                #pragma unroll
                for (int nf = 0; nf < 2; nf++)
                    acc[mf][nf] = __builtin_amdgcn_mfma_f32_16x16x32_bf16(af[mf], bfr[nf], acc[mf][nf], 0, 0, 0);
        }
    }

    // ---------------- epilogue ----------------
    if (EPI == 0) {
        const int part = n0 >> 8;            // 0=q 1=k 2=v
        const int h    = (n0 >> 6) & 3;
        const int b    = m0 >> 11;
        const int bh   = b * 4 + h;
        const float sc = (part == 0) ? 0.125f : 1.0f;   // fold attn scale into Q
        #pragma unroll
        for (int mf = 0; mf < 4; mf++)
            #pragma unroll
            for (int nf = 0; nf < 2; nf++) {
                const int d  = wn * 32 + nf * 16 + li;          // 0..63 head dim
                const float bv = bias[n0 + d];
                const int nr0 = (m0 & (Nn - 1)) + wm * 64 + mf * 16 + 4 * g;
                if (part < 2) {
                    u16* dst = (part == 0) ? bout : kout;
                    #pragma unroll
                    for (int r = 0; r < 4; r++)
                        dst[((size_t)bh * Nn + nr0 + r) * 64 + d] = f2bf((acc[mf][nf][r] + bv) * sc);
                } else {
                    const ushort4 o = make_ushort4(
                        f2bf(acc[mf][nf][0] + bv), f2bf(acc[mf][nf][1] + bv),
                        f2bf(acc[mf][nf][2] + bv), f2bf(acc[mf][nf][3] + bv));
                    *(ushort4*)(vtout + ((size_t)bh * 64 + d) * Nn + nr0) = o;
                }
            }
    } else {
        #pragma unroll
        for (int mf = 0; mf < 4; mf++)
            #pragma unroll
            for (int nf = 0; nf < 2; nf++) {
                const int j = n0 + wn * 32 + nf * 16 + li;
                const float bv = bias[j];
                #pragma unroll
                for (int r = 0; r < 4; r++) {
                    const int m = m0 + wm * 64 + mf * 16 + 4 * g + r;
                    float v = acc[mf][nf][r] + bv;
                    if (EPI == 1) {
                        v += res[((size_t)(m >> 11) * Cc + j) * Nn + (m & (Nn - 1))];
                        fout[(size_t)m * Nout + j] = v;
                    } else if (EPI == 2) {
                        v = 0.5f * v * (1.0f + erff(v * 0.70710678118f));
                        bout[(size_t)m * Nout + j] = f2bf(v);
                    } else if (EPI == 3) {
                        v += res[(size_t)m * Nout + j];
                        fout[(size_t)m * Nout + j] = v;
                    } else {
                        fout[(size_t)m * Nout + j] = v;
                    }
                }
            }
    }
}

// ---------------------------------------------------------------------------
// K2: MFMA flash attention, swapped QK^T (validated r11) + T14 async-STAGE:
// K/V tile kt+1 is loaded into registers while tile kt computes; the loop-top
// barrier is followed only by 4 ds_write_b128 (no global-load latency between
// barriers). Q pre-scaled by 0.125. Mask hoisted to last tile only.
// ---------------------------------------------------------------------------
__global__ __launch_bounds__(256) void attn_mfma_k(
    const u16* __restrict__ qb, const u16* __restrict__ kb,
    const u16* __restrict__ vtb, const int* __restrict__ lengths,
    u16* __restrict__ outb)
{
    __shared__ __align__(16) char QsB[8192];   // [64 q][64 d] bf16, swizzled
    __shared__ __align__(16) char KsB[8192];   // [64 k][64 d]
    __shared__ __align__(16) char VtB[8192];   // [64 d][64 k]
    __shared__ __align__(16) char PtB[8192];   // [64 q][64 k]  (wave-private rows)

    const int tid = threadIdx.x;
    const int qt = blockIdx.x;
    const int bh = blockIdx.y;
    const int b  = bh >> 2;
    const int len = lengths[b];
    const int w  = tid >> 6;
    const int l  = tid & 63;
    const int g  = l >> 4;
    const int li = l & 15;

    // staging geometry: thread handles chunks c0=tid, c1=tid+256 (row +32, same blk)
    const int srow = tid >> 3;          // 0..31
    const int sblk = (tid & 7) * 8;     // bf16 col 0..56

    for (int c = tid; c < 512; c += 256) {     // stage Q tile
        const int row = c >> 3, blk = c & 7;
        const uint4 v = *(const uint4*)(qb + ((size_t)bh * Nn + qt * 64 + row) * 64 + blk * 8);
        *(uint4*)(QsB + SWZB(row, blk * 8)) = v;
    }
    __syncthreads();
    // Q as B-operand fragment: col = query li (wave rows 16w..16w+15), k = dim
    bf16x8 bq[2];
    #pragma unroll
    for (int ks = 0; ks < 2; ks++)
        bq[ks] = *(const bf16x8*)(QsB + SWZB(16 * w + li, 32 * ks + 8 * g));

    // O^T accumulator: oacc[df][r] = O[query li][dim 16df+4g+r]
    f32x4 oacc[4];
    #pragma unroll
    for (int df = 0; df < 4; df++) oacc[df] = f32x4{0.f, 0.f, 0.f, 0.f};
    float m_run = NEG, l_run = 0.f;            // per-lane scalars (one query)

    const int ktmax = (len + 63) >> 6;

    // T14 prefetch registers: K/V tile in flight (2 chunks each per thread)
    uint4 kr0, kr1, vr0, vr1;
    {
        const size_t kbase = (size_t)bh * Nn * 64;
        kr0 = *(const uint4*)(kb + kbase + (size_t)(srow) * 64 + sblk);
        kr1 = *(const uint4*)(kb + kbase + (size_t)(srow + 32) * 64 + sblk);
        const size_t vbase = (size_t)bh * 64 * Nn;
        vr0 = *(const uint4*)(vtb + vbase + (size_t)(srow) * Nn + sblk);
        vr1 = *(const uint4*)(vtb + vbase + (size_t)(srow + 32) * Nn + sblk);
    }

    for (int kt = 0; kt < ktmax; ++kt) {
        __syncthreads();   // prev tile's K/V frag reads complete
        // write prefetched K/V regs -> LDS (only leg between the barriers)
        *(uint4*)(KsB + SWZB(srow,      sblk)) = kr0;
        *(uint4*)(KsB + SWZB(srow + 32, sblk)) = kr1;
        *(uint4*)(VtB + SWZB(srow,      sblk)) = vr0;
        *(uint4*)(VtB + SWZB(srow + 32, sblk)) = vr1;
        __syncthreads();
        // issue next tile's loads; latency hides under compute below
        if (kt + 1 < ktmax) {
            const size_t kbase = (size_t)bh * Nn * 64 + (size_t)(kt + 1) * 64 * 64;
            kr0 = *(const uint4*)(kb + kbase + (size_t)(srow) * 64 + sblk);
            kr1 = *(const uint4*)(kb + kbase + (size_t)(srow + 32) * 64 + sblk);
            const size_t vbase = (size_t)bh * 64 * Nn + (size_t)(kt + 1) * 64;
            vr0 = *(const uint4*)(vtb + vbase + (size_t)(srow) * Nn + sblk);
            vr1 = *(const uint4*)(vtb + vbase + (size_t)(srow + 32) * Nn + sblk);
        }

        // S^T[key][query] = mfma(A=K, B=Q): s[cf][r] = S^T[16cf+4g+r][li]
        f32x4 s[4];
        #pragma unroll
        for (int cf = 0; cf < 4; cf++) {
            f32x4 z = f32x4{0.f, 0.f, 0.f, 0.f};
            #pragma unroll
            for (int ks = 0; ks < 2; ks++) {
                const bf16x8 ak = *(const bf16x8*)(KsB + SWZB(16 * cf + li, 32 * ks + 8 * g));
                z = __builtin_amdgcn_mfma_f32_16x16x32_bf16(ak, bq[ks], z, 0, 0, 0);
            }
            s[cf] = z;
        }
        // key mask — only the (at most one) partial tile; wave-uniform branch
        if (kt * 64 + 64 > len) {
            #pragma unroll
            for (int cf = 0; cf < 4; cf++)
                #pragma unroll
                for (int r = 0; r < 4; r++)
                    if (kt * 64 + 16 * cf + 4 * g + r >= len) s[cf][r] = NEG;
        }
        // query-row max: 15 in-register fmax + 2 shfl (g-groups share query li)
        float mt = s[0][0];
        #pragma unroll
        for (int cf = 0; cf < 4; cf++)
            #pragma unroll
            for (int r = 0; r < 4; r++) mt = fmaxf(mt, s[cf][r]);
        mt = fmaxf(mt, __shfl_xor(mt, 16));
        mt = fmaxf(mt, __shfl_xor(mt, 32));
        const float mn = fmaxf(m_run, mt);
        const float f = __expf(m_run - mn);
        m_run = mn;
        // P = exp(S - m): pack consecutive keys to bf16 pairs, sum locally
        float sum = 0.f;
        u32 pw[4][2];
        #pragma unroll
        for (int cf = 0; cf < 4; cf++) {
            const float p0 = __expf(s[cf][0] - mn);
            const float p1 = __expf(s[cf][1] - mn);
            const float p2 = __expf(s[cf][2] - mn);
            const float p3 = __expf(s[cf][3] - mn);
            sum += (p0 + p1) + (p2 + p3);
            pw[cf][0] = pk2(p0, p1);
            pw[cf][1] = pk2(p2, p3);
        }
        sum += __shfl_xor(sum, 16);
        sum += __shfl_xor(sum, 32);
        l_run = l_run * f + sum;
        // write P^T rows (wave-private): 4 x b64, keys 16cf+4g..+3 of query li
        #pragma unroll
        for (int cf = 0; cf < 4; cf++) {
            uint2 pr; pr.x = pw[cf][0]; pr.y = pw[cf][1];
            *(uint2*)(PtB + SWZB(16 * w + li, 16 * cf + 4 * g)) = pr;
        }
        // rescale O^T
        #pragma unroll
        for (int df = 0; df < 4; df++)
            #pragma unroll
            for (int r = 0; r < 4; r++) oacc[df][r] *= f;
        // O^T += V^T · P^T  (A = V^T rows=dims, B = P^T col=query)
        bf16x8 bp[2];
        #pragma unroll
        for (int ks = 0; ks < 2; ks++)
            bp[ks] = *(const bf16x8*)(PtB + SWZB(16 * w + li, 32 * ks + 8 * g));
        #pragma unroll
        for (int df = 0; df < 4; df++)
            #pragma unroll
            for (int ks = 0; ks < 2; ks++) {
                const bf16x8 av = *(const bf16x8*)(VtB + SWZB(16 * df + li, 32 * ks + 8 * g));
                oacc[df] = __builtin_amdgcn_mfma_f32_16x16x32_bf16(av, bp[ks], oacc[df], 0, 0, 0);
            }
    }
    // epilogue: query = qt*64+16w+li owns dims 16df+4g+r -> 4x ushort4 stores
    const float inv = 1.f / l_run;
    const size_t base = ((size_t)b * Nn + qt * 64 + 16 * w + li) * Cc + (bh & 3) * 64;
    #pragma unroll
    for (int df = 0; df < 4; df++) {
        const ushort4 o = make_ushort4(f2bf(oacc[df][0] * inv), f2bf(oacc[df][1] * inv),
                                       f2bf(oacc[df][2] * inv), f2bf(oacc[df][3] * inv));
        *(ushort4*)(outb + base + 16 * df + 4 * g) = o;
    }
}

// ---------------------------------------------------------------------------
// LayerNorm: MODE 0 -> fp32 + bf16 outputs (ln1); MODE 1 -> bf16 only (ln2)
// ---------------------------------------------------------------------------
template<int MODE>
__global__ __launch_bounds__(256) void ln_k(
    const float* __restrict__ in, const float* __restrict__ w,
    const float* __restrict__ bc, float* __restrict__ outf,
    u16* __restrict__ outb)
{
    const int wave = threadIdx.x >> 6, lane = threadIdx.x & 63;
    const int row = blockIdx.x * 4 + wave;
    const float* p = in + (size_t)row * 256;
    const float v0 = p[lane], v1 = p[lane + 64], v2 = p[lane + 128], v3 = p[lane + 192];
    float s = v0 + v1 + v2 + v3;
    float s2 = v0 * v0 + v1 * v1 + v2 * v2 + v3 * v3;
    #pragma unroll
    for (int off = 32; off > 0; off >>= 1) {
        s  += __shfl_xor(s, off);
        s2 += __shfl_xor(s2, off);
    }
    const float mean = s * (1.f / 256.f);
    const float var  = s2 * (1.f / 256.f) - mean * mean;
    const float rstd = rsqrtf(var + 1e-5f);
    const float o0 = (v0 - mean) * rstd * w[lane]       + bc[lane];
    const float o1 = (v1 - mean) * rstd * w[lane + 64]  + bc[lane + 64];
    const float o2 = (v2 - mean) * rstd * w[lane + 128] + bc[lane + 128];
    const float o3 = (v3 - mean) * rstd * w[lane + 192] + bc[lane + 192];
    if (MODE == 0) {
        float* q = outf + (size_t)row * 256;
        q[lane] = o0; q[lane + 64] = o1; q[lane + 128] = o2; q[lane + 192] = o3;
    }
    u16* qb = outb + (size_t)row * 256;
    qb[lane] = f2bf(o0); qb[lane + 64] = f2bf(o1);
    qb[lane + 128] = f2bf(o2); qb[lane + 192] = f2bf(o3);
}

// ---------------------------------------------------------------------------
// K9: masked sequence softmax (unchanged)
// ---------------------------------------------------------------------------
__global__ __launch_bounds__(256) void smax_k(
    const float* __restrict__ logits, const int* __restrict__ lengths,
    float* __restrict__ outp)
{
    __shared__ float red[8];
    const int bk = blockIdx.x;
    const int b = bk >> 6, kc = bk & 63;
    const int len = lengths[b];
    const int tid = threadIdx.x;
    const int lane = tid & 63, wv = tid >> 6;

    float m = NEG;
    for (int n = tid; n < len; n += 256)
        m = fmaxf(m, logits[((size_t)b * Nn + n) * KK + kc]);
    #pragma unroll
    for (int off = 32; off > 0; off >>= 1) m = fmaxf(m, __shfl_xor(m, off));
    if (lane == 0) red[wv] = m;
    __syncthreads();
    m = fmaxf(fmaxf(red[0], red[1]), fmaxf(red[2], red[3]));

    float s = 0.f;
    for (int n = tid; n < len; n += 256)
        s += __expf(logits[((size_t)b * Nn + n) * KK + kc] - m);
    #pragma unroll
    for (int off = 32; off > 0; off >>= 1) s += __shfl_xor(s, off);
    if (lane == 0) red[4 + wv] = s;
    __syncthreads();
    s = red[4] + red[5] + red[6] + red[7];
    const float inv = 1.f / s;

    for (int n = tid; n < Nn; n += 256) {
        float o = 0.f;
        if (n < len)
            o = __expf(logits[((size_t)b * Nn + n) * KK + kc] - m) * inv;
        outp[((size_t)b * KK + kc) * Nn + n] = o;
    }
}

// ---------------------------------------------------------------------------
extern "C" void kernel_launch(void* const* d_in, const int* in_sizes, int n_in,
                              void* d_out, int out_size, void* d_ws, size_t ws_size,
                              hipStream_t stream)
{
    (void)in_sizes; (void)n_in; (void)out_size; (void)ws_size;
    const float* x      = (const float*)d_in[0];
    const int*   lens   = (const int*)d_in[1];
    const float* WQ     = (const float*)d_in[2];
    const float* WK     = (const float*)d_in[3];
    const float* WV     = (const float*)d_in[4];
    const float* in_w   = (const float*)d_in[5];
    const float* in_b   = (const float*)d_in[6];
    const float* op_w   = (const float*)d_in[7];
    const float* op_b   = (const float*)d_in[8];
    const float* ln1w   = (const float*)d_in[9];
    const float* ln1b   = (const float*)d_in[10];
    const float* ln2w   = (const float*)d_in[11];
    const float* ln2b   = (const float*)d_in[12];
    const float* ff1w   = (const float*)d_in[13];
    const float* ff1b   = (const float*)d_in[14];
    const float* ff2w   = (const float*)d_in[15];
    const float* ff2b   = (const float*)d_in[16];
    const float* prw    = (const float*)d_in[17];
    const float* prb    = (const float*)d_in[18];
    float* out = (float*)d_out;

    // workspace (lifetime-scheduled; peak 88 MB, < proven 97 MB)
    char* ws = (char*)d_ws;
    const size_t MB = 1024 * 1024;
    u16*   xb    = (u16*)(ws + 0);         // [M][256] bf16, 8 MB
    u16*   cwb   = (u16*)(ws +  8 * MB);   // [768][256] 384 KB
    u16*   opwb  = (u16*)(ws +  9 * MB);   // [256][256] 128 KB
    u16*   f1wb  = (u16*)(ws + 10 * MB);   // [512][256] 256 KB
    u16*   f2wb  = (u16*)(ws + 11 * MB);   // [256][512] 256 KB
    u16*   prwb  = (u16*)(ws + 12 * MB);   // [64][256]   32 KB
    u16*   qbuf  = (u16*)(ws + 16 * MB);   // 8 MB
    u16*   kbuf  = (u16*)(ws + 24 * MB);   // 8 MB
    u16*   vtbuf = (u16*)(ws + 32 * MB);   // 8 MB
    u16*   aob   = (u16*)(ws + 40 * MB);   // attn out bf16, 8 MB
    float* y1    = (float*)(ws + 48 * MB); // 16 MB
    float* h1    = (float*)(ws + 64 * MB); // 16 MB (fp32 residual)
    u16*   h1b   = (u16*)(ws + 80 * MB);   // 8 MB
    u16*   ffmid = (u16*)(ws + 16 * MB);   // [M][512] bf16 16 MB (q/k dead)
    float* y2    = (float*)(ws + 32 * MB); // 16 MB (vt/aob dead)
    u16*   h2b   = (u16*)(ws + 16 * MB);   // 8 MB (ffmid dead)
    float* logits= (float*)(ws + 24 * MB); // 4 MB

    xt_k<<<dim3(Nn / 64, Cc / 64, Bb), 256, 0, stream>>>(x, xb);
    combine_w_k<<<768, 256, 0, stream>>>(WQ, WK, WV, in_w, cwb);
    cvt4_k<<<256, 256, 0, stream>>>(op_w, opwb, 256 * 256,
                                    ff1w, f1wb, 512 * 256,
                                    ff2w, f2wb, 256 * 512,
                                    prw,  prwb, 64 * 256);
    gemm_mfma_k<0><<<dim3(Mm / 128, 768 / 64), 256, 0, stream>>>(
        xb, cwb, in_b, nullptr, nullptr, qbuf, kbuf, vtbuf, 768, 256);
    attn_mfma_k<<<dim3(Nn / 64, Bb * Hh), 256, 0, stream>>>(qbuf, kbuf, vtbuf, lens, aob);
    gemm_mfma_k<1><<<dim3(Mm / 128, 256 / 64), 256, 0, stream>>>(
        aob, opwb, op_b, x, y1, nullptr, nullptr, nullptr, 256, 256);
    ln_k<0><<<Mm / 4, 256, 0, stream>>>(y1, ln1w, ln1b, h1, h1b);
    gemm_mfma_k<2><<<dim3(Mm / 128, 512 / 64), 256, 0, stream>>>(
        h1b, f1wb, ff1b, nullptr, nullptr, ffmid, nullptr, nullptr, 512, 256);
    gemm_mfma_k<3><<<dim3(Mm / 128, 256 / 64), 256, 0, stream>>>(
        ffmid, f2wb, ff2b, h1, y2, nullptr, nullptr, nullptr, 256, 512);
    ln_k<1><<<Mm / 4, 256, 0, stream>>>(y2, ln2w, ln2b, nullptr, h2b);
    gemm_mfma_k<4><<<dim3(Mm / 128, 64 / 64), 256, 0, stream>>>(
        h2b, prwb, prb, nullptr, logits, nullptr, nullptr, nullptr, 64, 256);
    smax_k<<<Bb * KK, 256, 0, stream>>>(logits, lens, out);
}